// Round 1
// baseline (5717.629 us; speedup 1.0000x reference)
//
#include <hip/hip_runtime.h>
#include <math.h>

#define N_NODES 65536
#define F_IN 128
#define D_MODEL 256
#define E_EDGES 524288
#define EE_EDGES 589824   /* E + N self loops */
#define SEQ_LEN 2049
#define NHEAD 8
#define HDIM 32
#define NCLS 10

// ---------------------------------------------------------------------------
// Generic fp32 tiled GEMM: C[M,N] = A[M,K] @ B[K,N] (+bias) (+GELU) (+resid)
// 64x64 tile, BK=16, 256 threads, 4x4 per-thread microtile.
// Requires: K % 16 == 0, N % 64 == 0, A/B 16B-aligned. M edge guarded.
// ---------------------------------------------------------------------------
template<int ACT>   // 0 = none, 1 = exact GELU
__global__ __launch_bounds__(256) void sgemm(
    const float* __restrict__ A, const float* __restrict__ B,
    const float* __restrict__ bias, const float* __restrict__ Rsd,
    float* __restrict__ C, int M, int N, int K)
{
    __shared__ float As[16][68];
    __shared__ float Bs[16][68];
    const int tid = threadIdx.x;
    const int bn = blockIdx.x * 64;
    const int bm = blockIdx.y * 64;
    const int tr = (tid >> 4) * 4;
    const int tc = (tid & 15) * 4;
    const int arow = tid >> 2;
    const int ak   = (tid & 3) * 4;
    const int brow = tid >> 4;
    const int bcol = (tid & 15) * 4;
    float acc[4][4] = {};
    for (int k0 = 0; k0 < K; k0 += 16) {
        int gr = bm + arow;
        float4 av = make_float4(0.f, 0.f, 0.f, 0.f);
        if (gr < M) av = *(const float4*)(A + (size_t)gr * K + k0 + ak);
        As[ak + 0][arow] = av.x;
        As[ak + 1][arow] = av.y;
        As[ak + 2][arow] = av.z;
        As[ak + 3][arow] = av.w;
        float4 bv = *(const float4*)(B + (size_t)(k0 + brow) * N + bn + bcol);
        *(float4*)(&Bs[brow][bcol]) = bv;
        __syncthreads();
#pragma unroll
        for (int kk = 0; kk < 16; ++kk) {
            float4 a4 = *(const float4*)(&As[kk][tr]);
            float4 b4 = *(const float4*)(&Bs[kk][tc]);
            float a[4] = {a4.x, a4.y, a4.z, a4.w};
            float b[4] = {b4.x, b4.y, b4.z, b4.w};
#pragma unroll
            for (int i = 0; i < 4; ++i)
#pragma unroll
                for (int j = 0; j < 4; ++j)
                    acc[i][j] += a[i] * b[j];
        }
        __syncthreads();
    }
#pragma unroll
    for (int i = 0; i < 4; ++i) {
        int gr = bm + tr + i;
        if (gr >= M) break;
        float* cp = C + (size_t)gr * N + bn + tc;
        const float* rp = Rsd ? (Rsd + (size_t)gr * N + bn + tc) : nullptr;
#pragma unroll
        for (int j = 0; j < 4; ++j) {
            float v = acc[i][j];
            if (bias) v += bias[bn + tc + j];
            if (ACT == 1) v = 0.5f * v * (1.0f + erff(v * 0.70710678118654752f));
            if (rp) v += rp[j];
            cp[j] = v;
        }
    }
}

// ---------------------------------------------------------------------------
// bc = v[256] @ W[256,256]
// ---------------------------------------------------------------------------
__global__ void vecmat256(const float* __restrict__ v, const float* __restrict__ W,
                          float* __restrict__ out)
{
    int n = threadIdx.x;
    float acc = 0.f;
    for (int k = 0; k < 256; ++k) acc += v[k] * W[k * 256 + n];
    out[n] = acc;
}

// ---------------------------------------------------------------------------
// GAT pieces
// ---------------------------------------------------------------------------
__global__ void gat_init(float* __restrict__ emax, float* __restrict__ denom,
                         int* __restrict__ deg)
{
    int i = blockIdx.x * 256 + threadIdx.x;   // grid covers exactly N_NODES
    emax[i] = -1e30f;
    denom[i] = 0.f;
    deg[i] = 0;
}

// s_src/s_dst: per-node dot of WH row with a_src/a_dst. One wave per node.
__global__ __launch_bounds__(256) void gat_scores(
    const float* __restrict__ WH, const float* __restrict__ a_src,
    const float* __restrict__ a_dst, float* __restrict__ s_src,
    float* __restrict__ s_dst)
{
    int gid = blockIdx.x * 256 + threadIdx.x;
    int node = gid >> 6;
    int lane = gid & 63;
    const float* row = WH + (size_t)node * D_MODEL;
    float as = 0.f, ad = 0.f;
#pragma unroll
    for (int c = 0; c < 4; ++c) {
        int d = lane + 64 * c;
        float w = row[d];
        as += w * a_src[d];
        ad += w * a_dst[d];
    }
#pragma unroll
    for (int off = 32; off; off >>= 1) {
        as += __shfl_down(as, off);
        ad += __shfl_down(ad, off);
    }
    if (lane == 0) { s_src[node] = as; s_dst[node] = ad; }
}

__device__ __forceinline__ void atomicMaxFloat(float* addr, float val)
{
    int* ai = (int*)addr;
    int old = __float_as_int(*addr);
    while (__int_as_float(old) < val) {
        int prev = atomicCAS(ai, old, __float_as_int(val));
        if (prev == old) break;
        old = prev;
    }
}

__global__ void edge_pass1(const int* __restrict__ ei, const float* __restrict__ s_src,
                           const float* __restrict__ s_dst, float* __restrict__ e_buf,
                           float* __restrict__ emax, int* __restrict__ deg)
{
    int j = blockIdx.x * 256 + threadIdx.x;
    if (j >= EE_EDGES) return;
    int s, d;
    if (j < E_EDGES) { s = ei[j]; d = ei[E_EDGES + j]; }
    else { s = d = j - E_EDGES; }
    float e = s_src[s] + s_dst[d];
    e = (e > 0.f) ? e : 0.2f * e;           // leaky_relu 0.2
    e_buf[j] = e;
    atomicMaxFloat(&emax[d], e);
    atomicAdd(&deg[d], 1);
}

// exclusive scan over 65536 ints: 3 kernels
__global__ void scan1(const int* __restrict__ in, int* __restrict__ out_excl,
                      int* __restrict__ bsum)
{
    __shared__ int s[256];
    int t = threadIdx.x;
    int i = blockIdx.x * 256 + t;
    int v = in[i];
    s[t] = v;
    __syncthreads();
    for (int off = 1; off < 256; off <<= 1) {
        int u = (t >= off) ? s[t - off] : 0;
        __syncthreads();
        s[t] += u;
        __syncthreads();
    }
    out_excl[i] = s[t] - v;
    if (t == 255) bsum[blockIdx.x] = s[255];
}

__global__ void scan2(int* __restrict__ bsum)
{
    __shared__ int s[256];
    int t = threadIdx.x;
    int v = bsum[t];
    s[t] = v;
    __syncthreads();
    for (int off = 1; off < 256; off <<= 1) {
        int u = (t >= off) ? s[t - off] : 0;
        __syncthreads();
        s[t] += u;
        __syncthreads();
    }
    bsum[t] = s[t] - v;
}

__global__ void scan3(int* __restrict__ offs, const int* __restrict__ bsum,
                      int* __restrict__ cur)
{
    int i = blockIdx.x * 256 + threadIdx.x;
    int v = offs[i] + bsum[blockIdx.x];
    offs[i] = v;
    cur[i] = v;
}

__global__ void edge_pass2(const int* __restrict__ ei, const float* __restrict__ e_buf,
                           const float* __restrict__ emax, float* __restrict__ denom,
                           int* __restrict__ cur, int* __restrict__ csr_src,
                           float* __restrict__ csr_w)
{
    int j = blockIdx.x * 256 + threadIdx.x;
    if (j >= EE_EDGES) return;
    int s, d;
    if (j < E_EDGES) { s = ei[j]; d = ei[E_EDGES + j]; }
    else { s = d = j - E_EDGES; }
    float ee = __expf(e_buf[j] - emax[d]);
    atomicAdd(&denom[d], ee);
    int pos = atomicAdd(&cur[d], 1);
    csr_src[pos] = s;
    csr_w[pos] = ee;
}

// one wave per destination node; lanes split 256 dims into 4 chunks of 64
__global__ __launch_bounds__(256) void gat_aggregate(
    const float* __restrict__ WH, const int* __restrict__ csr_src,
    const float* __restrict__ csr_w, const int* __restrict__ offs,
    const int* __restrict__ deg, const float* __restrict__ denom,
    const float* __restrict__ b_gat, float* __restrict__ hout)
{
    int gid = blockIdx.x * 256 + threadIdx.x;
    int node = gid >> 6;
    int lane = gid & 63;
    float inv = 1.0f / denom[node];
    float a0 = 0.f, a1 = 0.f, a2 = 0.f, a3 = 0.f;
    int s0 = offs[node], e0 = s0 + deg[node];
    for (int k = s0; k < e0; ++k) {
        int src = csr_src[k];
        float alpha = csr_w[k] * inv;
        const float* row = WH + (size_t)src * D_MODEL;
        a0 += alpha * row[lane];
        a1 += alpha * row[lane + 64];
        a2 += alpha * row[lane + 128];
        a3 += alpha * row[lane + 192];
    }
    float* o = hout + (size_t)node * D_MODEL;
    o[lane]       = a0 + b_gat[lane];
    o[lane + 64]  = a1 + b_gat[lane + 64];
    o[lane + 128] = a2 + b_gat[lane + 128];
    o[lane + 192] = a3 + b_gat[lane + 192];
}

// ---------------------------------------------------------------------------
// LayerNorm over D=256, one block (256 thr) per row
// ---------------------------------------------------------------------------
__global__ __launch_bounds__(256) void ln_kernel(
    const float* __restrict__ X, const float* __restrict__ sc,
    const float* __restrict__ bi, float* __restrict__ Y)
{
    int row = blockIdx.x;
    int t = threadIdx.x;
    float x = X[(size_t)row * 256 + t];
    float sum = x, sq = x * x;
#pragma unroll
    for (int off = 32; off; off >>= 1) {
        sum += __shfl_down(sum, off);
        sq  += __shfl_down(sq, off);
    }
    __shared__ float rs[4], rq[4];
    if ((t & 63) == 0) { rs[t >> 6] = sum; rq[t >> 6] = sq; }
    __syncthreads();
    sum = rs[0] + rs[1] + rs[2] + rs[3];
    sq  = rq[0] + rq[1] + rq[2] + rq[3];
    float mean = sum * (1.f / 256.f);
    float var  = sq * (1.f / 256.f) - mean * mean;
    float r = rsqrtf(var + 1e-5f);
    Y[(size_t)row * 256 + t] = (x - mean) * r * sc[t] + bi[t];
}

// ---------------------------------------------------------------------------
// Flash attention fp32. Grid: (ceil(S/64), H). 256 thr = 64 q-rows x 4 subs.
// QKV layout per row: [q(8x32) | k(8x32) | v(8x32)] = 768 floats.
// ---------------------------------------------------------------------------
__global__ __launch_bounds__(256) void attn_kernel(
    const float* __restrict__ QKV, float* __restrict__ O)
{
    const int h = blockIdx.y;
    const int tid = threadIdx.x;
    const int qr = tid >> 2, sub = tid & 3;
    const int qrow = blockIdx.x * 64 + qr;
    __shared__ float Ks[64][32];
    __shared__ float Vs[64][32];
    const float scale = 0.17677669529663687f;  // 1/sqrt(32)
    float q[32];
    if (qrow < SEQ_LEN) {
        const float* qp = QKV + (size_t)qrow * 768 + h * 32;
#pragma unroll
        for (int d = 0; d < 32; d += 4) {
            float4 t4 = *(const float4*)(qp + d);
            q[d] = t4.x * scale; q[d+1] = t4.y * scale;
            q[d+2] = t4.z * scale; q[d+3] = t4.w * scale;
        }
    } else {
#pragma unroll
        for (int d = 0; d < 32; ++d) q[d] = 0.f;
    }
    float m = -1e30f, l = 0.f;
    float o[32];
#pragma unroll
    for (int d = 0; d < 32; ++d) o[d] = 0.f;

    const int ntiles = (SEQ_LEN + 63) >> 6;   // 33
    for (int t = 0; t < ntiles; ++t) {
        int base = t * 64;
        for (int i = tid; i < 2048; i += 256) {
            int r = i >> 5, d = i & 31;
            int krow = base + r;
            float kv = 0.f, vv = 0.f;
            if (krow < SEQ_LEN) {
                const float* p = QKV + (size_t)krow * 768 + 256 + h * 32 + d;
                kv = p[0];
                vv = p[256];
            }
            Ks[r][d] = kv;
            Vs[r][d] = vv;
        }
        __syncthreads();
        float sc[16];
        float mloc = -1e30f;
#pragma unroll
        for (int jj = 0; jj < 16; ++jj) {
            int j = sub * 16 + jj;
            float s;
            if (base + j < SEQ_LEN) {
                s = 0.f;
                const float4* kp = (const float4*)Ks[j];
#pragma unroll
                for (int d4 = 0; d4 < 8; ++d4) {
                    float4 k4 = kp[d4];
                    s += q[d4*4+0]*k4.x + q[d4*4+1]*k4.y
                       + q[d4*4+2]*k4.z + q[d4*4+3]*k4.w;
                }
            } else s = -1e30f;
            sc[jj] = s;
            mloc = fmaxf(mloc, s);
        }
        mloc = fmaxf(mloc, __shfl_xor(mloc, 1));
        mloc = fmaxf(mloc, __shfl_xor(mloc, 2));
        float newm = fmaxf(m, mloc);
        float fac = __expf(m - newm);
        l *= fac;
#pragma unroll
        for (int d = 0; d < 32; ++d) o[d] *= fac;
#pragma unroll
        for (int jj = 0; jj < 16; ++jj) {
            int j = sub * 16 + jj;
            float p = __expf(sc[jj] - newm);
            l += p;
            const float4* vp = (const float4*)Vs[j];
#pragma unroll
            for (int d4 = 0; d4 < 8; ++d4) {
                float4 v4 = vp[d4];
                o[d4*4+0] += p * v4.x; o[d4*4+1] += p * v4.y;
                o[d4*4+2] += p * v4.z; o[d4*4+3] += p * v4.w;
            }
        }
        m = newm;
        __syncthreads();
    }
    // combine partial l/o across the 4 subs of each row
    l += __shfl_xor(l, 1);
    l += __shfl_xor(l, 2);
#pragma unroll
    for (int d = 0; d < 32; ++d) {
        o[d] += __shfl_xor(o[d], 1);
        o[d] += __shfl_xor(o[d], 2);
    }
    if (qrow < SEQ_LEN) {
        float invl = 1.f / l;
        float* op = O + (size_t)qrow * 256 + h * 32;
#pragma unroll
        for (int dd = 0; dd < 8; ++dd) op[sub * 8 + dd] = o[sub * 8 + dd] * invl;
    }
}

__global__ void seed_seq(const float* __restrict__ cls, float* __restrict__ seq)
{
    seq[threadIdx.x] = cls[threadIdx.x];
}

__global__ void cls_head(const float* __restrict__ seq, const float* __restrict__ W,
                         const float* __restrict__ b, float* __restrict__ out)
{
    __shared__ float s[256];
    int t = threadIdx.x;
    s[t] = seq[t];
    __syncthreads();
    if (t < NCLS) {
        float acc = b[t];
        for (int k = 0; k < 256; ++k) acc += s[k] * W[k * NCLS + t];
        out[t] = acc;
    }
}

// ---------------------------------------------------------------------------
extern "C" void kernel_launch(void* const* d_in, const int* in_sizes, int n_in,
                              void* d_out, int out_size, void* d_ws, size_t ws_size,
                              hipStream_t stream)
{
    (void)in_sizes; (void)n_in; (void)out_size; (void)ws_size;
    const float* x       = (const float*)d_in[0];
    const int*   ei      = (const int*)d_in[1];
    const float* W_in    = (const float*)d_in[2];
    const float* b_in    = (const float*)d_in[3];
    const float* W_gat   = (const float*)d_in[4];
    const float* a_src   = (const float*)d_in[5];
    const float* a_dst   = (const float*)d_in[6];
    const float* b_gat   = (const float*)d_in[7];
    const float* W_emb   = (const float*)d_in[8];
    const float* b_emb   = (const float*)d_in[9];
    const float* cls_tok = (const float*)d_in[10];
    const float* ln1_s   = (const float*)d_in[11];
    const float* ln1_b   = (const float*)d_in[12];
    const float* Wqkv    = (const float*)d_in[13];
    const float* bqkv    = (const float*)d_in[14];
    const float* Wproj   = (const float*)d_in[15];
    const float* bproj   = (const float*)d_in[16];
    const float* ln2_s   = (const float*)d_in[17];
    const float* ln2_b   = (const float*)d_in[18];
    const float* W1      = (const float*)d_in[19];
    const float* b1      = (const float*)d_in[20];
    const float* W2      = (const float*)d_in[21];
    const float* b2      = (const float*)d_in[22];
    const float* W_cls   = (const float*)d_in[23];
    const float* b_cls   = (const float*)d_in[24];
    float* out = (float*)d_out;

    // -------- workspace layout (floats) --------
    float* ws = (float*)d_ws;
    float* bufWH = ws;                    // 16777216 (N x 256)
    float* bufH  = ws + 16777216;         // 16777216 (N x 256, GAT output)
    float* sm    = ws + 2 * 16777216;
    float* s_src = sm;                    // 65536
    float* s_dst = sm + 65536;
    float* emaxb = sm + 2 * 65536;
    float* denom = sm + 3 * 65536;
    float* e_buf = sm + 4 * 65536;        // 589824
    float* csr_w = e_buf + 589824;        // 589824
    float* Wc    = csr_w + 589824;        // 32768 (128x256)
    float* bc    = Wc + 32768;            // 256
    int*   deg     = (int*)(bc + 256);    // 65536
    int*   offs    = deg + 65536;         // 65536
    int*   cur     = offs + 65536;        // 65536
    int*   bsum    = cur + 65536;         // 256
    int*   csr_src = bsum + 256;          // 589824
    // transformer buffers alias bufWH (dead after gat_aggregate)
    float* seqb = bufWH;                  // 2049*256 = 524544
    float* Ybuf = bufWH + 524544;
    float* QKVb = bufWH + 2 * 524544;     // 2049*768 = 1573632
    float* Obuf = QKVb + 1573632;         // 524544
    float* MLPH = Obuf + 524544;          // 2049*1024 = 2098176

    // -------- GAT preprocessing --------
    gat_init<<<256, 256, 0, stream>>>(emaxb, denom, deg);
    // Wc = W_in @ W_gat ; bc = b_in @ W_gat  (fold the input linear into Wh)
    sgemm<0><<<dim3(4, 2), 256, 0, stream>>>(W_in, W_gat, nullptr, nullptr, Wc,
                                             128, 256, 256);
    vecmat256<<<1, 256, 0, stream>>>(b_in, W_gat, bc);
    // WH = x @ Wc + bc
    sgemm<0><<<dim3(4, 1024), 256, 0, stream>>>(x, Wc, bc, nullptr, bufWH,
                                                N_NODES, 256, 128);
    gat_scores<<<16384, 256, 0, stream>>>(bufWH, a_src, a_dst, s_src, s_dst);
    edge_pass1<<<EE_EDGES / 256, 256, 0, stream>>>(ei, s_src, s_dst, e_buf, emaxb, deg);
    scan1<<<256, 256, 0, stream>>>(deg, offs, bsum);
    scan2<<<1, 256, 0, stream>>>(bsum);
    scan3<<<256, 256, 0, stream>>>(offs, bsum, cur);
    edge_pass2<<<EE_EDGES / 256, 256, 0, stream>>>(ei, e_buf, emaxb, denom, cur,
                                                   csr_src, csr_w);
    gat_aggregate<<<16384, 256, 0, stream>>>(bufWH, csr_src, csr_w, offs, deg,
                                             denom, b_gat, bufH);

    // -------- token embedding: tok = h.reshape(2048,8192) @ W_emb + b_emb ----
    sgemm<0><<<dim3(4, 32), 256, 0, stream>>>(bufH, W_emb, b_emb, nullptr,
                                              seqb + 256, 2048, 256, 8192);
    seed_seq<<<1, 256, 0, stream>>>(cls_tok, seqb);

    // -------- transformer layers --------
    for (int i = 0; i < 8; ++i) {
        ln_kernel<<<SEQ_LEN, 256, 0, stream>>>(seqb, ln1_s + i * 256,
                                               ln1_b + i * 256, Ybuf);
        sgemm<0><<<dim3(12, 33), 256, 0, stream>>>(Ybuf, Wqkv + (size_t)i * 256 * 768,
                                                   bqkv + i * 768, nullptr, QKVb,
                                                   SEQ_LEN, 768, 256);
        attn_kernel<<<dim3(33, NHEAD), 256, 0, stream>>>(QKVb, Obuf);
        sgemm<0><<<dim3(4, 33), 256, 0, stream>>>(Obuf, Wproj + (size_t)i * 65536,
                                                  bproj + i * 256, seqb, seqb,
                                                  SEQ_LEN, 256, 256);
        ln_kernel<<<SEQ_LEN, 256, 0, stream>>>(seqb, ln2_s + i * 256,
                                               ln2_b + i * 256, Ybuf);
        sgemm<1><<<dim3(16, 33), 256, 0, stream>>>(Ybuf, W1 + (size_t)i * 262144,
                                                   b1 + i * 1024, nullptr, MLPH,
                                                   SEQ_LEN, 1024, 256);
        sgemm<0><<<dim3(4, 33), 256, 0, stream>>>(MLPH, W2 + (size_t)i * 262144,
                                                  b2 + i * 256, seqb, seqb,
                                                  SEQ_LEN, 256, 1024);
    }

    // -------- classifier head --------
    cls_head<<<1, 256, 0, stream>>>(seqb, W_cls, b_cls, out);
}

// Round 2
// 4822.834 us; speedup vs baseline: 1.1855x; 1.1855x over previous
//
#include <hip/hip_runtime.h>
#include <math.h>

#define N_NODES 65536
#define F_IN 128
#define D_MODEL 256
#define E_EDGES 524288
#define EE_EDGES 589824   /* E + N self loops */
#define SEQ_LEN 2049
#define NHEAD 8
#define HDIM 32
#define NCLS 10

typedef unsigned short u16;
typedef __attribute__((ext_vector_type(8))) short s8v;   // 8 x bf16 (4 VGPR)
typedef __attribute__((ext_vector_type(4))) float f4v;   // 4 x f32 acc

__device__ __forceinline__ u16 f2bf(float f)
{
    union { float f; unsigned u; } v; v.f = f;
    unsigned r = v.u + 0x7FFF + ((v.u >> 16) & 1);
    return (u16)(r >> 16);
}
__device__ __forceinline__ float bf2f(u16 h)
{
    union { unsigned u; float f; } v; v.u = ((unsigned)h) << 16;
    return v.f;
}

// ---------------------------------------------------------------------------
// prep: W [K,N] fp32 (row-major) -> Oh/Ol [N,K] bf16 hi/lo (transposed+split)
// grid: (K/64, N/64, nlayers)
// ---------------------------------------------------------------------------
__global__ __launch_bounds__(256) void prep_weight(
    const float* __restrict__ W, u16* __restrict__ Oh, u16* __restrict__ Ol,
    int K, int N, long long strideW, long long strideO)
{
    const float* Wz = W + (size_t)blockIdx.z * strideW;
    u16* Ohz = Oh + (size_t)blockIdx.z * strideO;
    u16* Olz = Ol + (size_t)blockIdx.z * strideO;
    __shared__ u16 th[64][68];
    __shared__ u16 tl[64][68];
    int kb = blockIdx.x * 64, nb = blockIdx.y * 64;
    int t = threadIdx.x;
    int kr = t >> 4, nc = (t & 15) * 4;
#pragma unroll
    for (int i = 0; i < 4; ++i) {
        int k = kr + i * 16;
        float4 v = *(const float4*)(Wz + (size_t)(kb + k) * N + nb + nc);
        float vv[4] = {v.x, v.y, v.z, v.w};
#pragma unroll
        for (int e = 0; e < 4; ++e) {
            u16 h = f2bf(vv[e]);
            th[k][nc + e] = h;
            tl[k][nc + e] = f2bf(vv[e] - bf2f(h));
        }
    }
    __syncthreads();
    int nr = t >> 4, kc = (t & 15) * 4;
#pragma unroll
    for (int i = 0; i < 4; ++i) {
        int n = nr + i * 16;
        uint2 oh, ol;
        oh.x = (unsigned)th[kc + 0][n] | ((unsigned)th[kc + 1][n] << 16);
        oh.y = (unsigned)th[kc + 2][n] | ((unsigned)th[kc + 3][n] << 16);
        ol.x = (unsigned)tl[kc + 0][n] | ((unsigned)tl[kc + 1][n] << 16);
        ol.y = (unsigned)tl[kc + 2][n] | ((unsigned)tl[kc + 3][n] << 16);
        *(uint2*)(Ohz + (size_t)(nb + n) * K + kb + kc) = oh;
        *(uint2*)(Olz + (size_t)(nb + n) * K + kb + kc) = ol;
    }
}

// ---------------------------------------------------------------------------
// Split-bf16 MFMA GEMM: C[M,N] = A[M,K] @ B[K,N] (+bias/GELU/residual/atomic)
// A fp32 row-major, split hi/lo in-kernel; B pre-transposed+split [N][K] bf16.
// Tile 64x64xBK32, 4 waves, each wave 32x32 via 2x2 mfma_f32_16x16x32_bf16.
// 3-term product (AhBh + AhBl + AlBh) => ~fp32 accuracy.
// grid: (N/64, ceil(M/64), ksplit); Kc = K/ksplit. ATOM=1 path: C preinited.
// ---------------------------------------------------------------------------
template<int ACT, int RES, int ATOM>
__global__ __launch_bounds__(256) void hgemm(
    const float* __restrict__ A, const u16* __restrict__ Bh,
    const u16* __restrict__ Bl, const float* __restrict__ bias,
    const float* __restrict__ Rsd, float* __restrict__ C,
    int M, int N, int K, int Kc)
{
    __shared__ __align__(16) u16 AhS[2048];
    __shared__ __align__(16) u16 AlS[2048];
    __shared__ __align__(16) u16 BhS[2048];
    __shared__ __align__(16) u16 BlS[2048];
    const int tid = threadIdx.x;
    const int bn = blockIdx.x * 64, bm = blockIdx.y * 64;
    const int kb = blockIdx.z * Kc;
    // staging indices: thread -> (row r, 16B chunk cch), XOR swizzle on chunk
    const int r = tid >> 2, cch = tid & 3;
    const int widx = r * 32 + ((cch ^ ((r >> 1) & 3)) << 3);
    // fragment indices
    const int w = tid >> 6, lane = tid & 63;
    const int wm = w >> 1, wn = w & 1;
    const int lr = lane & 15, lc = lane >> 4;
    const int ar0 = wm * 32 + lr, ar1 = ar0 + 16;
    const int nr0 = wn * 32 + lr, nr1 = nr0 + 16;
    const int ai0 = ar0 * 32 + ((lc ^ ((ar0 >> 1) & 3)) << 3);
    const int ai1 = ar1 * 32 + ((lc ^ ((ar1 >> 1) & 3)) << 3);
    const int bi0 = nr0 * 32 + ((lc ^ ((nr0 >> 1) & 3)) << 3);
    const int bi1 = nr1 * 32 + ((lc ^ ((nr1 >> 1) & 3)) << 3);

    f4v acc00 = {0.f, 0.f, 0.f, 0.f}, acc01 = acc00, acc10 = acc00, acc11 = acc00;

    const int gr = bm + r;
    const float* ap = A + (size_t)gr * K + kb + cch * 8;
    const u16* bhp = Bh + (size_t)(bn + r) * K + kb + cch * 8;
    const u16* blp = Bl + (size_t)(bn + r) * K + kb + cch * 8;

    for (int k0 = 0; k0 < Kc; k0 += 32) {
        float v[8] = {0.f, 0.f, 0.f, 0.f, 0.f, 0.f, 0.f, 0.f};
        if (gr < M) {
            float4 x0 = *(const float4*)ap;
            float4 x1 = *(const float4*)(ap + 4);
            v[0] = x0.x; v[1] = x0.y; v[2] = x0.z; v[3] = x0.w;
            v[4] = x1.x; v[5] = x1.y; v[6] = x1.z; v[7] = x1.w;
        }
        s8v hv, lv;
#pragma unroll
        for (int e = 0; e < 8; ++e) {
            u16 h = f2bf(v[e]);
            hv[e] = (short)h;
            lv[e] = (short)f2bf(v[e] - bf2f(h));
        }
        *(s8v*)&AhS[widx] = hv;
        *(s8v*)&AlS[widx] = lv;
        *(s8v*)&BhS[widx] = *(const s8v*)bhp;
        *(s8v*)&BlS[widx] = *(const s8v*)blp;
        __syncthreads();

        s8v a0h = *(s8v*)&AhS[ai0], a1h = *(s8v*)&AhS[ai1];
        s8v a0l = *(s8v*)&AlS[ai0], a1l = *(s8v*)&AlS[ai1];
        s8v b0h = *(s8v*)&BhS[bi0], b1h = *(s8v*)&BhS[bi1];
        s8v b0l = *(s8v*)&BlS[bi0], b1l = *(s8v*)&BlS[bi1];

        acc00 = __builtin_amdgcn_mfma_f32_16x16x32_bf16(a0h, b0h, acc00, 0, 0, 0);
        acc00 = __builtin_amdgcn_mfma_f32_16x16x32_bf16(a0h, b0l, acc00, 0, 0, 0);
        acc00 = __builtin_amdgcn_mfma_f32_16x16x32_bf16(a0l, b0h, acc00, 0, 0, 0);
        acc01 = __builtin_amdgcn_mfma_f32_16x16x32_bf16(a0h, b1h, acc01, 0, 0, 0);
        acc01 = __builtin_amdgcn_mfma_f32_16x16x32_bf16(a0h, b1l, acc01, 0, 0, 0);
        acc01 = __builtin_amdgcn_mfma_f32_16x16x32_bf16(a0l, b1h, acc01, 0, 0, 0);
        acc10 = __builtin_amdgcn_mfma_f32_16x16x32_bf16(a1h, b0h, acc10, 0, 0, 0);
        acc10 = __builtin_amdgcn_mfma_f32_16x16x32_bf16(a1h, b0l, acc10, 0, 0, 0);
        acc10 = __builtin_amdgcn_mfma_f32_16x16x32_bf16(a1l, b0h, acc10, 0, 0, 0);
        acc11 = __builtin_amdgcn_mfma_f32_16x16x32_bf16(a1h, b1h, acc11, 0, 0, 0);
        acc11 = __builtin_amdgcn_mfma_f32_16x16x32_bf16(a1h, b1l, acc11, 0, 0, 0);
        acc11 = __builtin_amdgcn_mfma_f32_16x16x32_bf16(a1l, b1h, acc11, 0, 0, 0);
        __syncthreads();
        ap += 32; bhp += 32; blp += 32;
    }

    // epilogue: C/D layout col=lane&15, row=(lane>>4)*4+j  [verified]
#pragma unroll
    for (int fg = 0; fg < 4; ++fg) {
        int f = fg >> 1, g = fg & 1;
        f4v a = (fg == 0) ? acc00 : (fg == 1) ? acc01 : (fg == 2) ? acc10 : acc11;
        int col = bn + wn * 32 + g * 16 + lr;
        int row0 = bm + wm * 32 + f * 16 + lc * 4;
#pragma unroll
        for (int j = 0; j < 4; ++j) {
            int rr = row0 + j;
            if (rr < M) {
                float vv = a[j];
                if (ATOM) {
                    atomicAdd(&C[(size_t)rr * N + col], vv);
                } else {
                    if (bias) vv += bias[col];
                    if (ACT == 1) vv = 0.5f * vv * (1.0f + erff(vv * 0.70710678118654752f));
                    if (RES) vv += Rsd[(size_t)rr * N + col];
                    C[(size_t)rr * N + col] = vv;
                }
            }
        }
    }
}

__global__ void init_bias(float* __restrict__ C, const float* __restrict__ bias,
                          int total, int nmask)
{
    int i = blockIdx.x * 256 + threadIdx.x;
    if (i < total) C[i] = bias[i & nmask];
}

// ---------------------------------------------------------------------------
// bc = v[256] @ W[256,256]
// ---------------------------------------------------------------------------
__global__ void vecmat256(const float* __restrict__ v, const float* __restrict__ W,
                          float* __restrict__ out)
{
    int n = threadIdx.x;
    float acc = 0.f;
    for (int k = 0; k < 256; ++k) acc += v[k] * W[k * 256 + n];
    out[n] = acc;
}

// ---------------------------------------------------------------------------
// GAT pieces (unchanged from round 1)
// ---------------------------------------------------------------------------
__global__ void gat_init(float* __restrict__ emax, float* __restrict__ denom,
                         int* __restrict__ deg)
{
    int i = blockIdx.x * 256 + threadIdx.x;
    emax[i] = -1e30f;
    denom[i] = 0.f;
    deg[i] = 0;
}

__global__ __launch_bounds__(256) void gat_scores(
    const float* __restrict__ WH, const float* __restrict__ a_src,
    const float* __restrict__ a_dst, float* __restrict__ s_src,
    float* __restrict__ s_dst)
{
    int gid = blockIdx.x * 256 + threadIdx.x;
    int node = gid >> 6;
    int lane = gid & 63;
    const float* row = WH + (size_t)node * D_MODEL;
    float as = 0.f, ad = 0.f;
#pragma unroll
    for (int c = 0; c < 4; ++c) {
        int d = lane + 64 * c;
        float w = row[d];
        as += w * a_src[d];
        ad += w * a_dst[d];
    }
#pragma unroll
    for (int off = 32; off; off >>= 1) {
        as += __shfl_down(as, off);
        ad += __shfl_down(ad, off);
    }
    if (lane == 0) { s_src[node] = as; s_dst[node] = ad; }
}

__device__ __forceinline__ void atomicMaxFloat(float* addr, float val)
{
    int* ai = (int*)addr;
    int old = __float_as_int(*addr);
    while (__int_as_float(old) < val) {
        int prev = atomicCAS(ai, old, __float_as_int(val));
        if (prev == old) break;
        old = prev;
    }
}

__global__ void edge_pass1(const int* __restrict__ ei, const float* __restrict__ s_src,
                           const float* __restrict__ s_dst, float* __restrict__ e_buf,
                           float* __restrict__ emax, int* __restrict__ deg)
{
    int j = blockIdx.x * 256 + threadIdx.x;
    if (j >= EE_EDGES) return;
    int s, d;
    if (j < E_EDGES) { s = ei[j]; d = ei[E_EDGES + j]; }
    else { s = d = j - E_EDGES; }
    float e = s_src[s] + s_dst[d];
    e = (e > 0.f) ? e : 0.2f * e;
    e_buf[j] = e;
    atomicMaxFloat(&emax[d], e);
    atomicAdd(&deg[d], 1);
}

__global__ void scan1(const int* __restrict__ in, int* __restrict__ out_excl,
                      int* __restrict__ bsum)
{
    __shared__ int s[256];
    int t = threadIdx.x;
    int i = blockIdx.x * 256 + t;
    int v = in[i];
    s[t] = v;
    __syncthreads();
    for (int off = 1; off < 256; off <<= 1) {
        int u = (t >= off) ? s[t - off] : 0;
        __syncthreads();
        s[t] += u;
        __syncthreads();
    }
    out_excl[i] = s[t] - v;
    if (t == 255) bsum[blockIdx.x] = s[255];
}

__global__ void scan2(int* __restrict__ bsum)
{
    __shared__ int s[256];
    int t = threadIdx.x;
    int v = bsum[t];
    s[t] = v;
    __syncthreads();
    for (int off = 1; off < 256; off <<= 1) {
        int u = (t >= off) ? s[t - off] : 0;
        __syncthreads();
        s[t] += u;
        __syncthreads();
    }
    bsum[t] = s[t] - v;
}

__global__ void scan3(int* __restrict__ offs, const int* __restrict__ bsum,
                      int* __restrict__ cur)
{
    int i = blockIdx.x * 256 + threadIdx.x;
    int v = offs[i] + bsum[blockIdx.x];
    offs[i] = v;
    cur[i] = v;
}

__global__ void edge_pass2(const int* __restrict__ ei, const float* __restrict__ e_buf,
                           const float* __restrict__ emax, float* __restrict__ denom,
                           int* __restrict__ cur, int* __restrict__ csr_src,
                           float* __restrict__ csr_w)
{
    int j = blockIdx.x * 256 + threadIdx.x;
    if (j >= EE_EDGES) return;
    int s, d;
    if (j < E_EDGES) { s = ei[j]; d = ei[E_EDGES + j]; }
    else { s = d = j - E_EDGES; }
    float ee = __expf(e_buf[j] - emax[d]);
    atomicAdd(&denom[d], ee);
    int pos = atomicAdd(&cur[d], 1);
    csr_src[pos] = s;
    csr_w[pos] = ee;
}

__global__ __launch_bounds__(256) void gat_aggregate(
    const float* __restrict__ WH, const int* __restrict__ csr_src,
    const float* __restrict__ csr_w, const int* __restrict__ offs,
    const int* __restrict__ deg, const float* __restrict__ denom,
    const float* __restrict__ b_gat, float* __restrict__ hout)
{
    int gid = blockIdx.x * 256 + threadIdx.x;
    int node = gid >> 6;
    int lane = gid & 63;
    float inv = 1.0f / denom[node];
    float a0 = 0.f, a1 = 0.f, a2 = 0.f, a3 = 0.f;
    int s0 = offs[node], e0 = s0 + deg[node];
    for (int k = s0; k < e0; ++k) {
        int src = csr_src[k];
        float alpha = csr_w[k] * inv;
        const float* row = WH + (size_t)src * D_MODEL;
        a0 += alpha * row[lane];
        a1 += alpha * row[lane + 64];
        a2 += alpha * row[lane + 128];
        a3 += alpha * row[lane + 192];
    }
    float* o = hout + (size_t)node * D_MODEL;
    o[lane]       = a0 + b_gat[lane];
    o[lane + 64]  = a1 + b_gat[lane + 64];
    o[lane + 128] = a2 + b_gat[lane + 128];
    o[lane + 192] = a3 + b_gat[lane + 192];
}

// ---------------------------------------------------------------------------
// LayerNorm over D=256, one block per row
// ---------------------------------------------------------------------------
__global__ __launch_bounds__(256) void ln_kernel(
    const float* __restrict__ X, const float* __restrict__ sc,
    const float* __restrict__ bi, float* __restrict__ Y)
{
    int row = blockIdx.x;
    int t = threadIdx.x;
    float x = X[(size_t)row * 256 + t];
    float sum = x, sq = x * x;
#pragma unroll
    for (int off = 32; off; off >>= 1) {
        sum += __shfl_down(sum, off);
        sq  += __shfl_down(sq, off);
    }
    __shared__ float rs[4], rq[4];
    if ((t & 63) == 0) { rs[t >> 6] = sum; rq[t >> 6] = sq; }
    __syncthreads();
    sum = rs[0] + rs[1] + rs[2] + rs[3];
    sq  = rq[0] + rq[1] + rq[2] + rq[3];
    float mean = sum * (1.f / 256.f);
    float var  = sq * (1.f / 256.f) - mean * mean;
    float r = rsqrtf(var + 1e-5f);
    Y[(size_t)row * 256 + t] = (x - mean) * r * sc[t] + bi[t];
}

// ---------------------------------------------------------------------------
// Flash attention fp32 (unchanged from round 1)
// ---------------------------------------------------------------------------
__global__ __launch_bounds__(256) void attn_kernel(
    const float* __restrict__ QKV, float* __restrict__ O)
{
    const int h = blockIdx.y;
    const int tid = threadIdx.x;
    const int qr = tid >> 2, sub = tid & 3;
    const int qrow = blockIdx.x * 64 + qr;
    __shared__ float Ks[64][32];
    __shared__ float Vs[64][32];
    const float scale = 0.17677669529663687f;
    float q[32];
    if (qrow < SEQ_LEN) {
        const float* qp = QKV + (size_t)qrow * 768 + h * 32;
#pragma unroll
        for (int d = 0; d < 32; d += 4) {
            float4 t4 = *(const float4*)(qp + d);
            q[d] = t4.x * scale; q[d+1] = t4.y * scale;
            q[d+2] = t4.z * scale; q[d+3] = t4.w * scale;
        }
    } else {
#pragma unroll
        for (int d = 0; d < 32; ++d) q[d] = 0.f;
    }
    float m = -1e30f, l = 0.f;
    float o[32];
#pragma unroll
    for (int d = 0; d < 32; ++d) o[d] = 0.f;

    const int ntiles = (SEQ_LEN + 63) >> 6;
    for (int t = 0; t < ntiles; ++t) {
        int base = t * 64;
        for (int i = tid; i < 2048; i += 256) {
            int rr = i >> 5, d = i & 31;
            int krow = base + rr;
            float kv = 0.f, vv = 0.f;
            if (krow < SEQ_LEN) {
                const float* p = QKV + (size_t)krow * 768 + 256 + h * 32 + d;
                kv = p[0];
                vv = p[256];
            }
            Ks[rr][d] = kv;
            Vs[rr][d] = vv;
        }
        __syncthreads();
        float sc[16];
        float mloc = -1e30f;
#pragma unroll
        for (int jj = 0; jj < 16; ++jj) {
            int j = sub * 16 + jj;
            float s;
            if (base + j < SEQ_LEN) {
                s = 0.f;
                const float4* kp = (const float4*)Ks[j];
#pragma unroll
                for (int d4 = 0; d4 < 8; ++d4) {
                    float4 k4 = kp[d4];
                    s += q[d4*4+0]*k4.x + q[d4*4+1]*k4.y
                       + q[d4*4+2]*k4.z + q[d4*4+3]*k4.w;
                }
            } else s = -1e30f;
            sc[jj] = s;
            mloc = fmaxf(mloc, s);
        }
        mloc = fmaxf(mloc, __shfl_xor(mloc, 1));
        mloc = fmaxf(mloc, __shfl_xor(mloc, 2));
        float newm = fmaxf(m, mloc);
        float fac = __expf(m - newm);
        l *= fac;
#pragma unroll
        for (int d = 0; d < 32; ++d) o[d] *= fac;
#pragma unroll
        for (int jj = 0; jj < 16; ++jj) {
            int j = sub * 16 + jj;
            float p = __expf(sc[jj] - newm);
            l += p;
            const float4* vp = (const float4*)Vs[j];
#pragma unroll
            for (int d4 = 0; d4 < 8; ++d4) {
                float4 v4 = vp[d4];
                o[d4*4+0] += p * v4.x; o[d4*4+1] += p * v4.y;
                o[d4*4+2] += p * v4.z; o[d4*4+3] += p * v4.w;
            }
        }
        m = newm;
        __syncthreads();
    }
    l += __shfl_xor(l, 1);
    l += __shfl_xor(l, 2);
#pragma unroll
    for (int d = 0; d < 32; ++d) {
        o[d] += __shfl_xor(o[d], 1);
        o[d] += __shfl_xor(o[d], 2);
    }
    if (qrow < SEQ_LEN) {
        float invl = 1.f / l;
        float* op = O + (size_t)qrow * 256 + h * 32;
#pragma unroll
        for (int dd = 0; dd < 8; ++dd) op[sub * 8 + dd] = o[sub * 8 + dd] * invl;
    }
}

__global__ void seed_seq(const float* __restrict__ cls, float* __restrict__ seq)
{
    seq[threadIdx.x] = cls[threadIdx.x];
}

__global__ void cls_head(const float* __restrict__ seq, const float* __restrict__ W,
                         const float* __restrict__ b, float* __restrict__ out)
{
    __shared__ float s[256];
    int t = threadIdx.x;
    s[t] = seq[t];
    __syncthreads();
    if (t < NCLS) {
        float acc = b[t];
        for (int k = 0; k < 256; ++k) acc += s[k] * W[k * NCLS + t];
        out[t] = acc;
    }
}

// ---------------------------------------------------------------------------
extern "C" void kernel_launch(void* const* d_in, const int* in_sizes, int n_in,
                              void* d_out, int out_size, void* d_ws, size_t ws_size,
                              hipStream_t stream)
{
    (void)in_sizes; (void)n_in; (void)out_size; (void)ws_size;
    const float* x       = (const float*)d_in[0];
    const int*   ei      = (const int*)d_in[1];
    const float* W_in    = (const float*)d_in[2];
    const float* b_in    = (const float*)d_in[3];
    const float* W_gat   = (const float*)d_in[4];
    const float* a_src   = (const float*)d_in[5];
    const float* a_dst   = (const float*)d_in[6];
    const float* b_gat   = (const float*)d_in[7];
    const float* W_emb   = (const float*)d_in[8];
    const float* b_emb   = (const float*)d_in[9];
    const float* cls_tok = (const float*)d_in[10];
    const float* ln1_s   = (const float*)d_in[11];
    const float* ln1_b   = (const float*)d_in[12];
    const float* Wqkv    = (const float*)d_in[13];
    const float* bqkv    = (const float*)d_in[14];
    const float* Wproj   = (const float*)d_in[15];
    const float* bproj   = (const float*)d_in[16];
    const float* ln2_s   = (const float*)d_in[17];
    const float* ln2_b   = (const float*)d_in[18];
    const float* W1      = (const float*)d_in[19];
    const float* b1      = (const float*)d_in[20];
    const float* W2      = (const float*)d_in[21];
    const float* b2      = (const float*)d_in[22];
    const float* W_cls   = (const float*)d_in[23];
    const float* b_cls   = (const float*)d_in[24];
    float* out = (float*)d_out;

    // -------- workspace layout (floats) --------
    float* ws = (float*)d_ws;
    float* bufWH = ws;                    // 16777216 (N x 256)
    float* bufH  = ws + 16777216;         // 16777216 (N x 256, GAT output)
    float* sm    = ws + 2 * 16777216;
    float* s_src = sm;                    // 65536
    float* s_dst = sm + 65536;
    float* emaxb = sm + 2 * 65536;
    float* denom = sm + 3 * 65536;
    float* e_buf = sm + 4 * 65536;        // 589824
    float* csr_w = e_buf + 589824;        // 589824
    float* Wc    = csr_w + 589824;        // 32768 (128x256)
    float* bc    = Wc + 32768;            // 256
    int*   deg     = (int*)(bc + 256);    // 65536
    int*   offs    = deg + 65536;         // 65536
    int*   cur     = offs + 65536;        // 65536
    int*   bsum    = cur + 65536;         // 256
    int*   csr_src = bsum + 256;          // 589824
    u16*   wgTh = (u16*)(csr_src + 589824);   // 65536 u16
    u16*   wgTl = wgTh + 65536;               // 65536
    u16*   wcTh = wgTh + 131072;              // 32768
    u16*   wcTl = wcTh + 32768;               // 32768
    // transformer buffers alias bufWH (dead after gat_aggregate)
    float* seqb = bufWH;                  // 2049*256 = 524544
    float* Ybuf = bufWH + 524544;
    float* QKVb = bufWH + 2 * 524544;     // 2049*768 = 1573632
    float* Obuf = QKVb + 1573632;         // 524544
    float* MLPH = Obuf + 524544;          // 2049*1024 = 2098176  (end 5245440)
    // transformer weights (bf16 hi/lo, transposed) also alias bufWH
    u16* wreg  = (u16*)(bufWH + 5500000);
    u16* embh  = wreg;                    // 2097152
    u16* embl  = wreg + 2097152;
    u16* qkvh  = wreg + 4194304;          // 8 x 196608
    u16* qkvl  = wreg + 5767168;
    u16* projh = wreg + 7340032;          // 8 x 65536
    u16* projl = wreg + 7864320;
    u16* w1h   = wreg + 8388608;          // 8 x 262144
    u16* w1l   = wreg + 10485760;
    u16* w2h   = wreg + 12582912;         // 8 x 262144
    u16* w2l   = wreg + 14680064;         // end 16777216 u16 = 8388608 floats

    // -------- GAT preprocessing --------
    gat_init<<<256, 256, 0, stream>>>(emaxb, denom, deg);
    // Wc = W_in @ W_gat ; bc = b_in @ W_gat
    prep_weight<<<dim3(4, 4, 1), 256, 0, stream>>>(W_gat, wgTh, wgTl, 256, 256, 0, 0);
    hgemm<0,0,0><<<dim3(4, 2, 1), 256, 0, stream>>>(W_in, wgTh, wgTl, nullptr,
                                                    nullptr, Wc, 128, 256, 256, 256);
    vecmat256<<<1, 256, 0, stream>>>(b_in, W_gat, bc);
    prep_weight<<<dim3(2, 4, 1), 256, 0, stream>>>(Wc, wcTh, wcTl, 128, 256, 0, 0);
    // WH = x @ Wc + bc
    hgemm<0,0,0><<<dim3(4, 1024, 1), 256, 0, stream>>>(x, wcTh, wcTl, bc, nullptr,
                                                       bufWH, N_NODES, 256, 128, 128);
    gat_scores<<<16384, 256, 0, stream>>>(bufWH, a_src, a_dst, s_src, s_dst);
    edge_pass1<<<EE_EDGES / 256, 256, 0, stream>>>(ei, s_src, s_dst, e_buf, emaxb, deg);
    scan1<<<256, 256, 0, stream>>>(deg, offs, bsum);
    scan2<<<1, 256, 0, stream>>>(bsum);
    scan3<<<256, 256, 0, stream>>>(offs, bsum, cur);
    edge_pass2<<<EE_EDGES / 256, 256, 0, stream>>>(ei, e_buf, emaxb, denom, cur,
                                                   csr_src, csr_w);
    gat_aggregate<<<16384, 256, 0, stream>>>(bufWH, csr_src, csr_w, offs, deg,
                                             denom, b_gat, bufH);

    // -------- weight prep (bufWH now dead above seqb/... region) --------
    prep_weight<<<dim3(128, 4, 1), 256, 0, stream>>>(W_emb, embh, embl, 8192, 256, 0, 0);
    prep_weight<<<dim3(4, 12, 8), 256, 0, stream>>>(Wqkv, qkvh, qkvl, 256, 768,
                                                    196608, 196608);
    prep_weight<<<dim3(4, 4, 8), 256, 0, stream>>>(Wproj, projh, projl, 256, 256,
                                                   65536, 65536);
    prep_weight<<<dim3(4, 16, 8), 256, 0, stream>>>(W1, w1h, w1l, 256, 1024,
                                                    262144, 262144);
    prep_weight<<<dim3(16, 4, 8), 256, 0, stream>>>(W2, w2h, w2l, 1024, 256,
                                                    262144, 262144);

    // -------- token embedding (split-K x8, atomic) --------
    init_bias<<<2048, 256, 0, stream>>>(seqb + 256, b_emb, 2048 * 256, 255);
    hgemm<0,0,1><<<dim3(4, 32, 8), 256, 0, stream>>>(bufH, embh, embl, nullptr,
                                                     nullptr, seqb + 256,
                                                     2048, 256, 8192, 1024);
    seed_seq<<<1, 256, 0, stream>>>(cls_tok, seqb);

    // -------- transformer layers --------
    for (int i = 0; i < 8; ++i) {
        ln_kernel<<<SEQ_LEN, 256, 0, stream>>>(seqb, ln1_s + i * 256,
                                               ln1_b + i * 256, Ybuf);
        hgemm<0,0,0><<<dim3(12, 33, 1), 256, 0, stream>>>(
            Ybuf, qkvh + (size_t)i * 196608, qkvl + (size_t)i * 196608,
            bqkv + i * 768, nullptr, QKVb, SEQ_LEN, 768, 256, 256);
        attn_kernel<<<dim3(33, NHEAD), 256, 0, stream>>>(QKVb, Obuf);
        hgemm<0,1,0><<<dim3(4, 33, 1), 256, 0, stream>>>(
            Obuf, projh + (size_t)i * 65536, projl + (size_t)i * 65536,
            bproj + i * 256, seqb, seqb, SEQ_LEN, 256, 256, 256);
        ln_kernel<<<SEQ_LEN, 256, 0, stream>>>(seqb, ln2_s + i * 256,
                                               ln2_b + i * 256, Ybuf);
        hgemm<1,0,0><<<dim3(16, 33, 1), 256, 0, stream>>>(
            Ybuf, w1h + (size_t)i * 262144, w1l + (size_t)i * 262144,
            b1 + i * 1024, nullptr, MLPH, SEQ_LEN, 1024, 256, 256);
        hgemm<0,1,0><<<dim3(4, 33, 1), 256, 0, stream>>>(
            MLPH, w2h + (size_t)i * 262144, w2l + (size_t)i * 262144,
            b2 + i * 256, seqb, seqb, SEQ_LEN, 256, 1024, 1024);
    }

    // -------- classifier head --------
    cls_head<<<1, 256, 0, stream>>>(seqb, W_cls, b_cls, out);
}

// Round 3
// 1488.280 us; speedup vs baseline: 3.8418x; 3.2405x over previous
//
#include <hip/hip_runtime.h>
#include <math.h>

#define N_NODES 65536
#define F_IN 128
#define D_MODEL 256
#define E_EDGES 524288
#define EE_EDGES 589824   /* E + N self loops */
#define SEQ_LEN 2049
#define SEQ_PAD 2112      /* 33*64 */
#define NHEAD 8
#define HDIM 32
#define NCLS 10

typedef unsigned short u16;
typedef __attribute__((ext_vector_type(8))) short s8v;   // 8 x bf16 (4 VGPR)
typedef __attribute__((ext_vector_type(4))) float f4v;   // 4 x f32 acc

__device__ __forceinline__ u16 f2bf(float f)
{
    union { float f; unsigned u; } v; v.f = f;
    unsigned r = v.u + 0x7FFF + ((v.u >> 16) & 1);
    return (u16)(r >> 16);
}
__device__ __forceinline__ float bf2f(u16 h)
{
    union { unsigned u; float f; } v; v.u = ((unsigned)h) << 16;
    return v.f;
}

// ---------------------------------------------------------------------------
// prep: W [K,N] fp32 (row-major) -> Oh/Ol [N,K] bf16 hi/lo (transposed+split)
// ---------------------------------------------------------------------------
__global__ __launch_bounds__(256) void prep_weight(
    const float* __restrict__ W, u16* __restrict__ Oh, u16* __restrict__ Ol,
    int K, int N, long long strideW, long long strideO)
{
    const float* Wz = W + (size_t)blockIdx.z * strideW;
    u16* Ohz = Oh + (size_t)blockIdx.z * strideO;
    u16* Olz = Ol + (size_t)blockIdx.z * strideO;
    __shared__ u16 th[64][68];
    __shared__ u16 tl[64][68];
    int kb = blockIdx.x * 64, nb = blockIdx.y * 64;
    int t = threadIdx.x;
    int kr = t >> 4, nc = (t & 15) * 4;
#pragma unroll
    for (int i = 0; i < 4; ++i) {
        int k = kr + i * 16;
        float4 v = *(const float4*)(Wz + (size_t)(kb + k) * N + nb + nc);
        float vv[4] = {v.x, v.y, v.z, v.w};
#pragma unroll
        for (int e = 0; e < 4; ++e) {
            u16 h = f2bf(vv[e]);
            th[k][nc + e] = h;
            tl[k][nc + e] = f2bf(vv[e] - bf2f(h));
        }
    }
    __syncthreads();
    int nr = t >> 4, kc = (t & 15) * 4;
#pragma unroll
    for (int i = 0; i < 4; ++i) {
        int n = nr + i * 16;
        uint2 oh, ol;
        oh.x = (unsigned)th[kc + 0][n] | ((unsigned)th[kc + 1][n] << 16);
        oh.y = (unsigned)th[kc + 2][n] | ((unsigned)th[kc + 3][n] << 16);
        ol.x = (unsigned)tl[kc + 0][n] | ((unsigned)tl[kc + 1][n] << 16);
        ol.y = (unsigned)tl[kc + 2][n] | ((unsigned)tl[kc + 3][n] << 16);
        *(uint2*)(Ohz + (size_t)(nb + n) * K + kb + kc) = oh;
        *(uint2*)(Olz + (size_t)(nb + n) * K + kb + kc) = ol;
    }
}

// ---------------------------------------------------------------------------
// Split-bf16 MFMA GEMM (3-term). OB=1: write bf16 (u16) output.
// ---------------------------------------------------------------------------
template<int ACT, int RES, int ATOM, int OB>
__global__ __launch_bounds__(256) void hgemm(
    const float* __restrict__ A, const u16* __restrict__ Bh,
    const u16* __restrict__ Bl, const float* __restrict__ bias,
    const float* __restrict__ Rsd, float* __restrict__ C,
    int M, int N, int K, int Kc)
{
    __shared__ __align__(16) u16 AhS[2048];
    __shared__ __align__(16) u16 AlS[2048];
    __shared__ __align__(16) u16 BhS[2048];
    __shared__ __align__(16) u16 BlS[2048];
    const int tid = threadIdx.x;
    const int bn = blockIdx.x * 64, bm = blockIdx.y * 64;
    const int kb = blockIdx.z * Kc;
    const int r = tid >> 2, cch = tid & 3;
    const int widx = r * 32 + ((cch ^ ((r >> 1) & 3)) << 3);
    const int w = tid >> 6, lane = tid & 63;
    const int wm = w >> 1, wn = w & 1;
    const int lr = lane & 15, lc = lane >> 4;
    const int ar0 = wm * 32 + lr, ar1 = ar0 + 16;
    const int nr0 = wn * 32 + lr, nr1 = nr0 + 16;
    const int ai0 = ar0 * 32 + ((lc ^ ((ar0 >> 1) & 3)) << 3);
    const int ai1 = ar1 * 32 + ((lc ^ ((ar1 >> 1) & 3)) << 3);
    const int bi0 = nr0 * 32 + ((lc ^ ((nr0 >> 1) & 3)) << 3);
    const int bi1 = nr1 * 32 + ((lc ^ ((nr1 >> 1) & 3)) << 3);

    f4v acc00 = {0.f, 0.f, 0.f, 0.f}, acc01 = acc00, acc10 = acc00, acc11 = acc00;

    const int gr = bm + r;
    const float* ap = A + (size_t)gr * K + kb + cch * 8;
    const u16* bhp = Bh + (size_t)(bn + r) * K + kb + cch * 8;
    const u16* blp = Bl + (size_t)(bn + r) * K + kb + cch * 8;

    for (int k0 = 0; k0 < Kc; k0 += 32) {
        float v[8] = {0.f, 0.f, 0.f, 0.f, 0.f, 0.f, 0.f, 0.f};
        if (gr < M) {
            float4 x0 = *(const float4*)ap;
            float4 x1 = *(const float4*)(ap + 4);
            v[0] = x0.x; v[1] = x0.y; v[2] = x0.z; v[3] = x0.w;
            v[4] = x1.x; v[5] = x1.y; v[6] = x1.z; v[7] = x1.w;
        }
        s8v hv, lv;
#pragma unroll
        for (int e = 0; e < 8; ++e) {
            u16 h = f2bf(v[e]);
            hv[e] = (short)h;
            lv[e] = (short)f2bf(v[e] - bf2f(h));
        }
        *(s8v*)&AhS[widx] = hv;
        *(s8v*)&AlS[widx] = lv;
        *(s8v*)&BhS[widx] = *(const s8v*)bhp;
        *(s8v*)&BlS[widx] = *(const s8v*)blp;
        __syncthreads();

        s8v a0h = *(s8v*)&AhS[ai0], a1h = *(s8v*)&AhS[ai1];
        s8v a0l = *(s8v*)&AlS[ai0], a1l = *(s8v*)&AlS[ai1];
        s8v b0h = *(s8v*)&BhS[bi0], b1h = *(s8v*)&BhS[bi1];
        s8v b0l = *(s8v*)&BlS[bi0], b1l = *(s8v*)&BlS[bi1];

        acc00 = __builtin_amdgcn_mfma_f32_16x16x32_bf16(a0h, b0h, acc00, 0, 0, 0);
        acc00 = __builtin_amdgcn_mfma_f32_16x16x32_bf16(a0h, b0l, acc00, 0, 0, 0);
        acc00 = __builtin_amdgcn_mfma_f32_16x16x32_bf16(a0l, b0h, acc00, 0, 0, 0);
        acc01 = __builtin_amdgcn_mfma_f32_16x16x32_bf16(a0h, b1h, acc01, 0, 0, 0);
        acc01 = __builtin_amdgcn_mfma_f32_16x16x32_bf16(a0h, b1l, acc01, 0, 0, 0);
        acc01 = __builtin_amdgcn_mfma_f32_16x16x32_bf16(a0l, b1h, acc01, 0, 0, 0);
        acc10 = __builtin_amdgcn_mfma_f32_16x16x32_bf16(a1h, b0h, acc10, 0, 0, 0);
        acc10 = __builtin_amdgcn_mfma_f32_16x16x32_bf16(a1h, b0l, acc10, 0, 0, 0);
        acc10 = __builtin_amdgcn_mfma_f32_16x16x32_bf16(a1l, b0h, acc10, 0, 0, 0);
        acc11 = __builtin_amdgcn_mfma_f32_16x16x32_bf16(a1h, b1h, acc11, 0, 0, 0);
        acc11 = __builtin_amdgcn_mfma_f32_16x16x32_bf16(a1h, b1l, acc11, 0, 0, 0);
        acc11 = __builtin_amdgcn_mfma_f32_16x16x32_bf16(a1l, b1h, acc11, 0, 0, 0);
        __syncthreads();
        ap += 32; bhp += 32; blp += 32;
    }

#pragma unroll
    for (int fg = 0; fg < 4; ++fg) {
        int f = fg >> 1, g = fg & 1;
        f4v a = (fg == 0) ? acc00 : (fg == 1) ? acc01 : (fg == 2) ? acc10 : acc11;
        int col = bn + wn * 32 + g * 16 + lr;
        int row0 = bm + wm * 32 + f * 16 + lc * 4;
#pragma unroll
        for (int j = 0; j < 4; ++j) {
            int rr = row0 + j;
            if (rr < M) {
                float vv = a[j];
                if (ATOM) {
                    atomicAdd(&C[(size_t)rr * N + col], vv);
                } else {
                    if (bias) vv += bias[col];
                    if (ACT == 1) vv = 0.5f * vv * (1.0f + erff(vv * 0.70710678118654752f));
                    if (RES) vv += Rsd[(size_t)rr * N + col];
                    if (OB) ((u16*)C)[(size_t)rr * N + col] = f2bf(vv);
                    else    C[(size_t)rr * N + col] = vv;
                }
            }
        }
    }
}

__global__ void init_bias(float* __restrict__ C, const float* __restrict__ bias,
                          int total, int nmask)
{
    int i = blockIdx.x * 256 + threadIdx.x;
    if (i < total) C[i] = bias[i & nmask];
}

__global__ void pad_zero_u32(unsigned* __restrict__ p, int n)
{
    int i = blockIdx.x * 256 + threadIdx.x;
    if (i < n) p[i] = 0u;
}

// ---------------------------------------------------------------------------
// bc = v[256] @ W[256,256]
// ---------------------------------------------------------------------------
__global__ void vecmat256(const float* __restrict__ v, const float* __restrict__ W,
                          float* __restrict__ out)
{
    int n = threadIdx.x;
    float acc = 0.f;
    for (int k = 0; k < 256; ++k) acc += v[k] * W[k * 256 + n];
    out[n] = acc;
}

// ---------------------------------------------------------------------------
// GAT pieces
// ---------------------------------------------------------------------------
__global__ void gat_init(float* __restrict__ emax, float* __restrict__ denom,
                         int* __restrict__ deg)
{
    int i = blockIdx.x * 256 + threadIdx.x;
    emax[i] = -1e30f;
    denom[i] = 0.f;
    deg[i] = 0;
}

__global__ __launch_bounds__(256) void gat_scores(
    const float* __restrict__ WH, const float* __restrict__ a_src,
    const float* __restrict__ a_dst, float* __restrict__ s_src,
    float* __restrict__ s_dst)
{
    int gid = blockIdx.x * 256 + threadIdx.x;
    int node = gid >> 6;
    int lane = gid & 63;
    const float* row = WH + (size_t)node * D_MODEL;
    float as = 0.f, ad = 0.f;
#pragma unroll
    for (int c = 0; c < 4; ++c) {
        int d = lane + 64 * c;
        float w = row[d];
        as += w * a_src[d];
        ad += w * a_dst[d];
    }
#pragma unroll
    for (int off = 32; off; off >>= 1) {
        as += __shfl_down(as, off);
        ad += __shfl_down(ad, off);
    }
    if (lane == 0) { s_src[node] = as; s_dst[node] = ad; }
}

__device__ __forceinline__ void atomicMaxFloat(float* addr, float val)
{
    int* ai = (int*)addr;
    int old = __float_as_int(*addr);
    while (__int_as_float(old) < val) {
        int prev = atomicCAS(ai, old, __float_as_int(val));
        if (prev == old) break;
        old = prev;
    }
}

__global__ void edge_pass1(const int* __restrict__ ei, const float* __restrict__ s_src,
                           const float* __restrict__ s_dst, float* __restrict__ e_buf,
                           float* __restrict__ emax, int* __restrict__ deg)
{
    int j = blockIdx.x * 256 + threadIdx.x;
    if (j >= EE_EDGES) return;
    int s, d;
    if (j < E_EDGES) { s = ei[j]; d = ei[E_EDGES + j]; }
    else { s = d = j - E_EDGES; }
    float e = s_src[s] + s_dst[d];
    e = (e > 0.f) ? e : 0.2f * e;
    e_buf[j] = e;
    atomicMaxFloat(&emax[d], e);
    atomicAdd(&deg[d], 1);
}

__global__ void scan1(const int* __restrict__ in, int* __restrict__ out_excl,
                      int* __restrict__ bsum)
{
    __shared__ int s[256];
    int t = threadIdx.x;
    int i = blockIdx.x * 256 + t;
    int v = in[i];
    s[t] = v;
    __syncthreads();
    for (int off = 1; off < 256; off <<= 1) {
        int u = (t >= off) ? s[t - off] : 0;
        __syncthreads();
        s[t] += u;
        __syncthreads();
    }
    out_excl[i] = s[t] - v;
    if (t == 255) bsum[blockIdx.x] = s[255];
}

__global__ void scan2(int* __restrict__ bsum)
{
    __shared__ int s[256];
    int t = threadIdx.x;
    int v = bsum[t];
    s[t] = v;
    __syncthreads();
    for (int off = 1; off < 256; off <<= 1) {
        int u = (t >= off) ? s[t - off] : 0;
        __syncthreads();
        s[t] += u;
        __syncthreads();
    }
    bsum[t] = s[t] - v;
}

__global__ void scan3(int* __restrict__ offs, const int* __restrict__ bsum,
                      int* __restrict__ cur)
{
    int i = blockIdx.x * 256 + threadIdx.x;
    int v = offs[i] + bsum[blockIdx.x];
    offs[i] = v;
    cur[i] = v;
}

__global__ void edge_pass2(const int* __restrict__ ei, const float* __restrict__ e_buf,
                           const float* __restrict__ emax, float* __restrict__ denom,
                           int* __restrict__ cur, int* __restrict__ csr_src,
                           float* __restrict__ csr_w)
{
    int j = blockIdx.x * 256 + threadIdx.x;
    if (j >= EE_EDGES) return;
    int s, d;
    if (j < E_EDGES) { s = ei[j]; d = ei[E_EDGES + j]; }
    else { s = d = j - E_EDGES; }
    float ee = __expf(e_buf[j] - emax[d]);
    atomicAdd(&denom[d], ee);
    int pos = atomicAdd(&cur[d], 1);
    csr_src[pos] = s;
    csr_w[pos] = ee;
}

__global__ __launch_bounds__(256) void gat_aggregate(
    const float* __restrict__ WH, const int* __restrict__ csr_src,
    const float* __restrict__ csr_w, const int* __restrict__ offs,
    const int* __restrict__ deg, const float* __restrict__ denom,
    const float* __restrict__ b_gat, float* __restrict__ hout)
{
    int gid = blockIdx.x * 256 + threadIdx.x;
    int node = gid >> 6;
    int lane = gid & 63;
    float inv = 1.0f / denom[node];
    float a0 = 0.f, a1 = 0.f, a2 = 0.f, a3 = 0.f;
    int s0 = offs[node], e0 = s0 + deg[node];
    for (int k = s0; k < e0; ++k) {
        int src = csr_src[k];
        float alpha = csr_w[k] * inv;
        const float* row = WH + (size_t)src * D_MODEL;
        a0 += alpha * row[lane];
        a1 += alpha * row[lane + 64];
        a2 += alpha * row[lane + 128];
        a3 += alpha * row[lane + 192];
    }
    float* o = hout + (size_t)node * D_MODEL;
    o[lane]       = a0 + b_gat[lane];
    o[lane + 64]  = a1 + b_gat[lane + 64];
    o[lane + 128] = a2 + b_gat[lane + 128];
    o[lane + 192] = a3 + b_gat[lane + 192];
}

// ---------------------------------------------------------------------------
// LayerNorm over D=256, one block per row
// ---------------------------------------------------------------------------
__global__ __launch_bounds__(256) void ln_kernel(
    const float* __restrict__ X, const float* __restrict__ sc,
    const float* __restrict__ bi, float* __restrict__ Y)
{
    int row = blockIdx.x;
    int t = threadIdx.x;
    float x = X[(size_t)row * 256 + t];
    float sum = x, sq = x * x;
#pragma unroll
    for (int off = 32; off; off >>= 1) {
        sum += __shfl_down(sum, off);
        sq  += __shfl_down(sq, off);
    }
    __shared__ float rs[4], rq[4];
    if ((t & 63) == 0) { rs[t >> 6] = sum; rq[t >> 6] = sq; }
    __syncthreads();
    sum = rs[0] + rs[1] + rs[2] + rs[3];
    sq  = rq[0] + rq[1] + rq[2] + rq[3];
    float mean = sum * (1.f / 256.f);
    float var  = sq * (1.f / 256.f) - mean * mean;
    float r = rsqrtf(var + 1e-5f);
    Y[(size_t)row * 256 + t] = (x - mean) * r * sc[t] + bi[t];
}

// ---------------------------------------------------------------------------
// MFMA flash attention, bf16 Q/K/V/P, fp32 softmax + accum.
// QKV: bf16 [SEQ_PAD][768] (q|k|v per head h at h*32 / 256+h*32 / 512+h*32).
// Grid (33, 8); 256 thr = 4 waves x 16 q-rows. KV tile = 64.
// Per wave/tile: 4 QK mfma (16x16x32) + 4 PV mfma; P via swizzled LDS.
// ---------------------------------------------------------------------------
__global__ __launch_bounds__(256) void mfma_attn(
    const u16* __restrict__ QKV, float* __restrict__ O)
{
    __shared__ __align__(16) u16 Ks[64 * 32];    // [kv][32], chunk-swizzled
    __shared__ __align__(16) u16 Vt[32 * 72];    // [d][72]  (kv + pad)
    __shared__ __align__(16) u16 Ps[4 * 16 * 72];// per-wave [16 q][72]
    const int tid = threadIdx.x;
    const int w = tid >> 6, lane = tid & 63;
    const int g = lane >> 4, ql = lane & 15;
    const int h = blockIdx.y;
    const int qbase = blockIdx.x * 64 + w * 16;
    const float scale = 0.17677669529663687f;    // 1/sqrt(32)

    // Q fragment: A-operand, row q = ql, k-dim d = g*8..+7
    int qrow = qbase + ql; if (qrow > SEQ_LEN - 1) qrow = SEQ_LEN - 1;
    const s8v qfrag = *(const s8v*)(QKV + (size_t)qrow * 768 + h * 32 + g * 8);

    f4v o0 = {0.f, 0.f, 0.f, 0.f}, o1 = o0;
    float m[4], l[4];
#pragma unroll
    for (int r = 0; r < 4; ++r) { m[r] = -1e30f; l[r] = 0.f; }

    const int sr = tid >> 2, sc_ = tid & 3;          // staging row/chunk
    const int kslot = sc_ ^ ((sr >> 1) & 3);
    u16* const psw = &Ps[w * 1152];

    for (int t = 0; t < 33; ++t) {
        __syncthreads();
        {   // stage K (swizzled row-major) and V (transposed) for this tile
            int grow = t * 64 + sr;                  // < SEQ_PAD, pad rows are 0
            const u16* kp = QKV + (size_t)grow * 768 + 256 + h * 32 + sc_ * 8;
            s8v kvv = *(const s8v*)kp;
            s8v vvv = *(const s8v*)(kp + 256);
            *(s8v*)&Ks[sr * 32 + kslot * 8] = kvv;
#pragma unroll
            for (int e = 0; e < 8; ++e) Vt[(sc_ * 8 + e) * 72 + sr] = (u16)vvv[e];
        }
        __syncthreads();

        // ---- QK^T: 4 mfma, D: col=kv(ql), row=q(g*4+r) ----
        f4v s[4];
        const f4v zz = {0.f, 0.f, 0.f, 0.f};
#pragma unroll
        for (int c = 0; c < 4; ++c) {
            int kvloc = c * 16 + ql;
            s8v kf = *(s8v*)&Ks[kvloc * 32 + ((g ^ ((kvloc >> 1) & 3)) << 3)];
            s[c] = __builtin_amdgcn_mfma_f32_16x16x32_bf16(qfrag, kf, zz, 0, 0, 0);
            int kvg = t * 64 + kvloc;
            bool valid = (kvg < SEQ_LEN);
#pragma unroll
            for (int r = 0; r < 4; ++r)
                s[c][r] = valid ? s[c][r] * scale : -1e30f;
        }

        // ---- online softmax (per q = g*4+r; row spread over 16 lanes) ----
        float mloc[4];
#pragma unroll
        for (int r = 0; r < 4; ++r) {
            float v = fmaxf(fmaxf(s[0][r], s[1][r]), fmaxf(s[2][r], s[3][r]));
            v = fmaxf(v, __shfl_xor(v, 1));
            v = fmaxf(v, __shfl_xor(v, 2));
            v = fmaxf(v, __shfl_xor(v, 4));
            v = fmaxf(v, __shfl_xor(v, 8));
            mloc[r] = v;
        }
        float fac[4];
#pragma unroll
        for (int r = 0; r < 4; ++r) {
            float mn = fmaxf(m[r], mloc[r]);
            fac[r] = __expf(m[r] - mn);
            m[r] = mn;
        }
#pragma unroll
        for (int c = 0; c < 4; ++c)
#pragma unroll
            for (int r = 0; r < 4; ++r)
                s[c][r] = __expf(s[c][r] - m[r]);
#pragma unroll
        for (int r = 0; r < 4; ++r) {
            float ls = s[0][r] + s[1][r] + s[2][r] + s[3][r];
            ls += __shfl_xor(ls, 1);
            ls += __shfl_xor(ls, 2);
            ls += __shfl_xor(ls, 4);
            ls += __shfl_xor(ls, 8);
            l[r] = l[r] * fac[r] + ls;
            o0[r] *= fac[r];
            o1[r] *= fac[r];
        }

        // ---- P -> LDS (bf16), per-wave private tile ----
#pragma unroll
        for (int c = 0; c < 4; ++c)
#pragma unroll
            for (int r = 0; r < 4; ++r)
                psw[(g * 4 + r) * 72 + c * 16 + ql] = f2bf(s[c][r]);

        // ---- PV: A=P[q][kv] contiguous, B=Vt[d][kv] contiguous ----
#pragma unroll
        for (int kch = 0; kch < 2; ++kch) {
            s8v pf = *(s8v*)&psw[ql * 72 + kch * 32 + g * 8];
            s8v v0 = *(s8v*)&Vt[ql * 72 + kch * 32 + g * 8];
            s8v v1 = *(s8v*)&Vt[(16 + ql) * 72 + kch * 32 + g * 8];
            o0 = __builtin_amdgcn_mfma_f32_16x16x32_bf16(pf, v0, o0, 0, 0, 0);
            o1 = __builtin_amdgcn_mfma_f32_16x16x32_bf16(pf, v1, o1, 0, 0, 0);
        }
    }

    // ---- epilogue ----
#pragma unroll
    for (int r = 0; r < 4; ++r) {
        int q = qbase + g * 4 + r;
        if (q < SEQ_LEN) {
            float invl = 1.f / l[r];
            float* op = O + (size_t)q * 256 + h * 32;
            op[ql] = o0[r] * invl;
            op[16 + ql] = o1[r] * invl;
        }
    }
}

__global__ void seed_seq(const float* __restrict__ cls, float* __restrict__ seq)
{
    seq[threadIdx.x] = cls[threadIdx.x];
}

__global__ void cls_head(const float* __restrict__ seq, const float* __restrict__ W,
                         const float* __restrict__ b, float* __restrict__ out)
{
    __shared__ float s[256];
    int t = threadIdx.x;
    s[t] = seq[t];
    __syncthreads();
    if (t < NCLS) {
        float acc = b[t];
        for (int k = 0; k < 256; ++k) acc += s[k] * W[k * NCLS + t];
        out[t] = acc;
    }
}

// ---------------------------------------------------------------------------
extern "C" void kernel_launch(void* const* d_in, const int* in_sizes, int n_in,
                              void* d_out, int out_size, void* d_ws, size_t ws_size,
                              hipStream_t stream)
{
    (void)in_sizes; (void)n_in; (void)out_size; (void)ws_size;
    const float* x       = (const float*)d_in[0];
    const int*   ei      = (const int*)d_in[1];
    const float* W_in    = (const float*)d_in[2];
    const float* b_in    = (const float*)d_in[3];
    const float* W_gat   = (const float*)d_in[4];
    const float* a_src   = (const float*)d_in[5];
    const float* a_dst   = (const float*)d_in[6];
    const float* b_gat   = (const float*)d_in[7];
    const float* W_emb   = (const float*)d_in[8];
    const float* b_emb   = (const float*)d_in[9];
    const float* cls_tok = (const float*)d_in[10];
    const float* ln1_s   = (const float*)d_in[11];
    const float* ln1_b   = (const float*)d_in[12];
    const float* Wqkv    = (const float*)d_in[13];
    const float* bqkv    = (const float*)d_in[14];
    const float* Wproj   = (const float*)d_in[15];
    const float* bproj   = (const float*)d_in[16];
    const float* ln2_s   = (const float*)d_in[17];
    const float* ln2_b   = (const float*)d_in[18];
    const float* W1      = (const float*)d_in[19];
    const float* b1      = (const float*)d_in[20];
    const float* W2      = (const float*)d_in[21];
    const float* b2      = (const float*)d_in[22];
    const float* W_cls   = (const float*)d_in[23];
    const float* b_cls   = (const float*)d_in[24];
    float* out = (float*)d_out;

    // -------- workspace layout (floats) --------
    float* ws = (float*)d_ws;
    float* bufWH = ws;                    // 16777216 (N x 256)
    float* bufH  = ws + 16777216;         // 16777216 (N x 256, GAT output)
    float* sm    = ws + 2 * 16777216;
    float* s_src = sm;                    // 65536
    float* s_dst = sm + 65536;
    float* emaxb = sm + 2 * 65536;
    float* denom = sm + 3 * 65536;
    float* e_buf = sm + 4 * 65536;        // 589824
    float* csr_w = e_buf + 589824;        // 589824
    float* Wc    = csr_w + 589824;        // 32768 (128x256)
    float* bc    = Wc + 32768;            // 256
    int*   deg     = (int*)(bc + 256);    // 65536
    int*   offs    = deg + 65536;         // 65536
    int*   cur     = offs + 65536;        // 65536
    int*   bsum    = cur + 65536;         // 256
    int*   csr_src = bsum + 256;          // 589824
    u16*   wgTh = (u16*)(csr_src + 589824);   // 65536 u16
    u16*   wgTl = wgTh + 65536;               // 65536
    u16*   wcTh = wgTh + 131072;              // 32768
    u16*   wcTl = wcTh + 32768;               // 32768
    // transformer buffers alias bufWH (dead after gat_aggregate)
    float* seqb = bufWH;                  // 2049*256 = 524544
    float* Ybuf = bufWH + 524544;
    u16*   QKVb = (u16*)(bufWH + 2 * 524544);  // bf16 [2112][768] = 1622016 u16
    float* Obuf = bufWH + 2 * 524544 + 1573632;  // 524544
    float* MLPH = Obuf + 524544;          // 2049*1024
    // transformer weights (bf16 hi/lo, transposed) also alias bufWH
    u16* wreg  = (u16*)(bufWH + 5500000);
    u16* embh  = wreg;                    // 2097152
    u16* embl  = wreg + 2097152;
    u16* qkvh  = wreg + 4194304;          // 8 x 196608
    u16* qkvl  = wreg + 5767168;
    u16* projh = wreg + 7340032;          // 8 x 65536
    u16* projl = wreg + 7864320;
    u16* w1h   = wreg + 8388608;          // 8 x 262144
    u16* w1l   = wreg + 10485760;
    u16* w2h   = wreg + 12582912;         // 8 x 262144
    u16* w2l   = wreg + 14680064;         // end 16777216 u16

    // -------- GAT preprocessing --------
    gat_init<<<256, 256, 0, stream>>>(emaxb, denom, deg);
    prep_weight<<<dim3(4, 4, 1), 256, 0, stream>>>(W_gat, wgTh, wgTl, 256, 256, 0, 0);
    hgemm<0,0,0,0><<<dim3(4, 2, 1), 256, 0, stream>>>(W_in, wgTh, wgTl, nullptr,
                                                      nullptr, Wc, 128, 256, 256, 256);
    vecmat256<<<1, 256, 0, stream>>>(b_in, W_gat, bc);
    prep_weight<<<dim3(2, 4, 1), 256, 0, stream>>>(Wc, wcTh, wcTl, 128, 256, 0, 0);
    hgemm<0,0,0,0><<<dim3(4, 1024, 1), 256, 0, stream>>>(x, wcTh, wcTl, bc, nullptr,
                                                         bufWH, N_NODES, 256, 128, 128);
    gat_scores<<<16384, 256, 0, stream>>>(bufWH, a_src, a_dst, s_src, s_dst);
    edge_pass1<<<EE_EDGES / 256, 256, 0, stream>>>(ei, s_src, s_dst, e_buf, emaxb, deg);
    scan1<<<256, 256, 0, stream>>>(deg, offs, bsum);
    scan2<<<1, 256, 0, stream>>>(bsum);
    scan3<<<256, 256, 0, stream>>>(offs, bsum, cur);
    edge_pass2<<<EE_EDGES / 256, 256, 0, stream>>>(ei, e_buf, emaxb, denom, cur,
                                                   csr_src, csr_w);
    gat_aggregate<<<16384, 256, 0, stream>>>(bufWH, csr_src, csr_w, offs, deg,
                                             denom, b_gat, bufH);

    // -------- weight prep --------
    prep_weight<<<dim3(128, 4, 1), 256, 0, stream>>>(W_emb, embh, embl, 8192, 256, 0, 0);
    prep_weight<<<dim3(4, 12, 8), 256, 0, stream>>>(Wqkv, qkvh, qkvl, 256, 768,
                                                    196608, 196608);
    prep_weight<<<dim3(4, 4, 8), 256, 0, stream>>>(Wproj, projh, projl, 256, 256,
                                                   65536, 65536);
    prep_weight<<<dim3(4, 16, 8), 256, 0, stream>>>(W1, w1h, w1l, 256, 1024,
                                                    262144, 262144);
    prep_weight<<<dim3(16, 4, 8), 256, 0, stream>>>(W2, w2h, w2l, 1024, 256,
                                                    262144, 262144);

    // -------- token embedding (split-K x8, atomic) --------
    init_bias<<<2048, 256, 0, stream>>>(seqb + 256, b_emb, 2048 * 256, 255);
    hgemm<0,0,1,0><<<dim3(4, 32, 8), 256, 0, stream>>>(bufH, embh, embl, nullptr,
                                                       nullptr, seqb + 256,
                                                       2048, 256, 8192, 1024);
    seed_seq<<<1, 256, 0, stream>>>(cls_tok, seqb);

    // zero QKV pad rows (2049..2111) once: (SEQ_PAD-SEQ_LEN)*768/2 u32
    pad_zero_u32<<<95, 256, 0, stream>>>(
        (unsigned*)(QKVb + (size_t)SEQ_LEN * 768), (SEQ_PAD - SEQ_LEN) * 768 / 2);

    // -------- transformer layers --------
    for (int i = 0; i < 8; ++i) {
        ln_kernel<<<SEQ_LEN, 256, 0, stream>>>(seqb, ln1_s + i * 256,
                                               ln1_b + i * 256, Ybuf);
        hgemm<0,0,0,1><<<dim3(12, 33, 1), 256, 0, stream>>>(
            Ybuf, qkvh + (size_t)i * 196608, qkvl + (size_t)i * 196608,
            bqkv + i * 768, nullptr, (float*)QKVb, SEQ_LEN, 768, 256, 256);
        mfma_attn<<<dim3(33, NHEAD), 256, 0, stream>>>(QKVb, Obuf);
        hgemm<0,1,0,0><<<dim3(4, 33, 1), 256, 0, stream>>>(
            Obuf, projh + (size_t)i * 65536, projl + (size_t)i * 65536,
            bproj + i * 256, seqb, seqb, SEQ_LEN, 256, 256, 256);
        ln_kernel<<<SEQ_LEN, 256, 0, stream>>>(seqb, ln2_s + i * 256,
                                               ln2_b + i * 256, Ybuf);
        hgemm<1,0,0,0><<<dim3(16, 33, 1), 256, 0, stream>>>(
            Ybuf, w1h + (size_t)i * 262144, w1l + (size_t)i * 262144,
            b1 + i * 1024, nullptr, MLPH, SEQ_LEN, 1024, 256, 256);
        hgemm<0,1,0,0><<<dim3(4, 33, 1), 256, 0, stream>>>(
            MLPH, w2h + (size_t)i * 262144, w2l + (size_t)i * 262144,
            b2 + i * 256, seqb, seqb, SEQ_LEN, 256, 1024, 1024);
    }

    // -------- classifier head --------
    cls_head<<<1, 256, 0, stream>>>(seqb, W_cls, b_cls, out);
}

// Round 4
// 1336.405 us; speedup vs baseline: 4.2784x; 1.1136x over previous
//
#include <hip/hip_runtime.h>
#include <math.h>

#define N_NODES 65536
#define F_IN 128
#define D_MODEL 256
#define E_EDGES 524288
#define EE_EDGES 589824   /* E + N self loops */
#define SEQ_LEN 2049
#define SEQ_PAD 2112      /* 33*64 */
#define NHEAD 8
#define HDIM 32
#define NCLS 10

typedef unsigned short u16;
typedef __attribute__((ext_vector_type(8))) short s8v;   // 8 x bf16 (4 VGPR)
typedef __attribute__((ext_vector_type(4))) float f4v;   // 4 x f32 acc

__device__ __forceinline__ u16 f2bf(float f)
{
    union { float f; unsigned u; } v; v.f = f;
    unsigned r = v.u + 0x7FFF + ((v.u >> 16) & 1);
    return (u16)(r >> 16);
}
__device__ __forceinline__ float bf2f(u16 h)
{
    union { unsigned u; float f; } v; v.u = ((unsigned)h) << 16;
    return v.f;
}

// ---------------------------------------------------------------------------
// prep: W [K,N] fp32 (row-major) -> Oh/Ol [N,K] bf16 hi/lo (transposed+split)
// ---------------------------------------------------------------------------
__global__ __launch_bounds__(256) void prep_weight(
    const float* __restrict__ W, u16* __restrict__ Oh, u16* __restrict__ Ol,
    int K, int N, long long strideW, long long strideO)
{
    const float* Wz = W + (size_t)blockIdx.z * strideW;
    u16* Ohz = Oh + (size_t)blockIdx.z * strideO;
    u16* Olz = Ol + (size_t)blockIdx.z * strideO;
    __shared__ u16 th[64][68];
    __shared__ u16 tl[64][68];
    int kb = blockIdx.x * 64, nb = blockIdx.y * 64;
    int t = threadIdx.x;
    int kr = t >> 4, nc = (t & 15) * 4;
#pragma unroll
    for (int i = 0; i < 4; ++i) {
        int k = kr + i * 16;
        float4 v = *(const float4*)(Wz + (size_t)(kb + k) * N + nb + nc);
        float vv[4] = {v.x, v.y, v.z, v.w};
#pragma unroll
        for (int e = 0; e < 4; ++e) {
            u16 h = f2bf(vv[e]);
            th[k][nc + e] = h;
            tl[k][nc + e] = f2bf(vv[e] - bf2f(h));
        }
    }
    __syncthreads();
    int nr = t >> 4, kc = (t & 15) * 4;
#pragma unroll
    for (int i = 0; i < 4; ++i) {
        int n = nr + i * 16;
        uint2 oh, ol;
        oh.x = (unsigned)th[kc + 0][n] | ((unsigned)th[kc + 1][n] << 16);
        oh.y = (unsigned)th[kc + 2][n] | ((unsigned)th[kc + 3][n] << 16);
        ol.x = (unsigned)tl[kc + 0][n] | ((unsigned)tl[kc + 1][n] << 16);
        ol.y = (unsigned)tl[kc + 2][n] | ((unsigned)tl[kc + 3][n] << 16);
        *(uint2*)(Ohz + (size_t)(nb + n) * K + kb + kc) = oh;
        *(uint2*)(Olz + (size_t)(nb + n) * K + kb + kc) = ol;
    }
}

// ---------------------------------------------------------------------------
// Split-bf16 MFMA GEMM (3-term).
// APRE=0: A fp32 (split in-kernel). APRE=1: A = u16 hi ptr, Al2 = lo ptr.
// OB: 0 = fp32 C; 1 = bf16 C; 2 = bf16 hi/lo (C, C2).
// ATOM=1: fp32 atomicAdd into preinitialized C (bias/res prefolded).
// ---------------------------------------------------------------------------
template<int ACT, int RES, int ATOM, int OB, int APRE>
__global__ __launch_bounds__(256) void hgemm(
    const void* __restrict__ A, const u16* __restrict__ Al2,
    const u16* __restrict__ Bh, const u16* __restrict__ Bl,
    const float* __restrict__ bias, const float* __restrict__ Rsd,
    float* __restrict__ C, u16* __restrict__ C2,
    int M, int N, int K, int Kc)
{
    __shared__ __align__(16) u16 AhS[2048];
    __shared__ __align__(16) u16 AlS[2048];
    __shared__ __align__(16) u16 BhS[2048];
    __shared__ __align__(16) u16 BlS[2048];
    const int tid = threadIdx.x;
    const int bn = blockIdx.x * 64, bm = blockIdx.y * 64;
    const int kb = blockIdx.z * Kc;
    const int r = tid >> 2, cch = tid & 3;
    const int widx = r * 32 + ((cch ^ ((r >> 1) & 3)) << 3);
    const int w = tid >> 6, lane = tid & 63;
    const int wm = w >> 1, wn = w & 1;
    const int lr = lane & 15, lc = lane >> 4;
    const int ar0 = wm * 32 + lr, ar1 = ar0 + 16;
    const int nr0 = wn * 32 + lr, nr1 = nr0 + 16;
    const int ai0 = ar0 * 32 + ((lc ^ ((ar0 >> 1) & 3)) << 3);
    const int ai1 = ar1 * 32 + ((lc ^ ((ar1 >> 1) & 3)) << 3);
    const int bi0 = nr0 * 32 + ((lc ^ ((nr0 >> 1) & 3)) << 3);
    const int bi1 = nr1 * 32 + ((lc ^ ((nr1 >> 1) & 3)) << 3);

    f4v acc00 = {0.f, 0.f, 0.f, 0.f}, acc01 = acc00, acc10 = acc00, acc11 = acc00;

    const int gr = bm + r;
    const float* apf = (const float*)A + (size_t)gr * K + kb + cch * 8;
    const u16*   aph = (const u16*)A + (size_t)gr * K + kb + cch * 8;
    const u16*   apl = Al2 ? Al2 + (size_t)gr * K + kb + cch * 8 : (const u16*)0;
    const u16* bhp = Bh + (size_t)(bn + r) * K + kb + cch * 8;
    const u16* blp = Bl + (size_t)(bn + r) * K + kb + cch * 8;

    for (int k0 = 0; k0 < Kc; k0 += 32) {
        s8v hv = {0, 0, 0, 0, 0, 0, 0, 0}, lv = hv;
        if (APRE) {
            if (gr < M) { hv = *(const s8v*)aph; lv = *(const s8v*)apl; }
        } else {
            float v[8] = {0.f, 0.f, 0.f, 0.f, 0.f, 0.f, 0.f, 0.f};
            if (gr < M) {
                float4 x0 = *(const float4*)apf;
                float4 x1 = *(const float4*)(apf + 4);
                v[0] = x0.x; v[1] = x0.y; v[2] = x0.z; v[3] = x0.w;
                v[4] = x1.x; v[5] = x1.y; v[6] = x1.z; v[7] = x1.w;
            }
#pragma unroll
            for (int e = 0; e < 8; ++e) {
                u16 h = f2bf(v[e]);
                hv[e] = (short)h;
                lv[e] = (short)f2bf(v[e] - bf2f(h));
            }
        }
        *(s8v*)&AhS[widx] = hv;
        *(s8v*)&AlS[widx] = lv;
        *(s8v*)&BhS[widx] = *(const s8v*)bhp;
        *(s8v*)&BlS[widx] = *(const s8v*)blp;
        __syncthreads();

        s8v a0h = *(s8v*)&AhS[ai0], a1h = *(s8v*)&AhS[ai1];
        s8v a0l = *(s8v*)&AlS[ai0], a1l = *(s8v*)&AlS[ai1];
        s8v b0h = *(s8v*)&BhS[bi0], b1h = *(s8v*)&BhS[bi1];
        s8v b0l = *(s8v*)&BlS[bi0], b1l = *(s8v*)&BlS[bi1];

        acc00 = __builtin_amdgcn_mfma_f32_16x16x32_bf16(a0h, b0h, acc00, 0, 0, 0);
        acc00 = __builtin_amdgcn_mfma_f32_16x16x32_bf16(a0h, b0l, acc00, 0, 0, 0);
        acc00 = __builtin_amdgcn_mfma_f32_16x16x32_bf16(a0l, b0h, acc00, 0, 0, 0);
        acc01 = __builtin_amdgcn_mfma_f32_16x16x32_bf16(a0h, b1h, acc01, 0, 0, 0);
        acc01 = __builtin_amdgcn_mfma_f32_16x16x32_bf16(a0h, b1l, acc01, 0, 0, 0);
        acc01 = __builtin_amdgcn_mfma_f32_16x16x32_bf16(a0l, b1h, acc01, 0, 0, 0);
        acc10 = __builtin_amdgcn_mfma_f32_16x16x32_bf16(a1h, b0h, acc10, 0, 0, 0);
        acc10 = __builtin_amdgcn_mfma_f32_16x16x32_bf16(a1h, b0l, acc10, 0, 0, 0);
        acc10 = __builtin_amdgcn_mfma_f32_16x16x32_bf16(a1l, b0h, acc10, 0, 0, 0);
        acc11 = __builtin_amdgcn_mfma_f32_16x16x32_bf16(a1h, b1h, acc11, 0, 0, 0);
        acc11 = __builtin_amdgcn_mfma_f32_16x16x32_bf16(a1h, b1l, acc11, 0, 0, 0);
        acc11 = __builtin_amdgcn_mfma_f32_16x16x32_bf16(a1l, b1h, acc11, 0, 0, 0);
        __syncthreads();
        apf += 32; aph += 32; apl += 32; bhp += 32; blp += 32;
    }

#pragma unroll
    for (int fg = 0; fg < 4; ++fg) {
        int f = fg >> 1, g = fg & 1;
        f4v a = (fg == 0) ? acc00 : (fg == 1) ? acc01 : (fg == 2) ? acc10 : acc11;
        int col = bn + wn * 32 + g * 16 + lr;
        int row0 = bm + wm * 32 + f * 16 + lc * 4;
#pragma unroll
        for (int j = 0; j < 4; ++j) {
            int rr = row0 + j;
            if (rr < M) {
                float vv = a[j];
                if (ATOM) {
                    atomicAdd(&C[(size_t)rr * N + col], vv);
                } else {
                    if (bias) vv += bias[col];
                    if (ACT == 1) vv = 0.5f * vv * (1.0f + erff(vv * 0.70710678118654752f));
                    if (RES) vv += Rsd[(size_t)rr * N + col];
                    if (OB == 1) {
                        ((u16*)C)[(size_t)rr * N + col] = f2bf(vv);
                    } else if (OB == 2) {
                        u16 h = f2bf(vv);
                        ((u16*)C)[(size_t)rr * N + col] = h;
                        C2[(size_t)rr * N + col] = f2bf(vv - bf2f(h));
                    } else {
                        C[(size_t)rr * N + col] = vv;
                    }
                }
            }
        }
    }
}

__global__ void init_bias(float* __restrict__ C, const float* __restrict__ bias,
                          int total, int nmask)
{
    int i = blockIdx.x * 256 + threadIdx.x;
    if (i < total) C[i] = bias[i & nmask];
}

__global__ void pad_zero_u32(unsigned* __restrict__ p, int n)
{
    int i = blockIdx.x * 256 + threadIdx.x;
    if (i < n) p[i] = 0u;
}

__global__ void vecmat256(const float* __restrict__ v, const float* __restrict__ W,
                          float* __restrict__ out)
{
    int n = threadIdx.x;
    float acc = 0.f;
    for (int k = 0; k < 256; ++k) acc += v[k] * W[k * 256 + n];
    out[n] = acc;
}

// ---------------------------------------------------------------------------
// GAT pieces
// ---------------------------------------------------------------------------
__global__ void gat_init(float* __restrict__ emax, float* __restrict__ denom,
                         int* __restrict__ deg)
{
    int i = blockIdx.x * 256 + threadIdx.x;
    emax[i] = -1e30f;
    denom[i] = 0.f;
    deg[i] = 0;
}

// WH now bf16. Each lane handles dims lane*4..lane*4+3 (one 8B load).
__global__ __launch_bounds__(256) void gat_scores(
    const u16* __restrict__ WH, const float* __restrict__ a_src,
    const float* __restrict__ a_dst, float* __restrict__ s_src,
    float* __restrict__ s_dst)
{
    int gid = blockIdx.x * 256 + threadIdx.x;
    int node = gid >> 6;
    int lane = gid & 63;
    uint2 rv = *(const uint2*)(WH + (size_t)node * D_MODEL + (lane << 2));
    float d0 = __uint_as_float(rv.x << 16);
    float d1 = __uint_as_float(rv.x & 0xffff0000u);
    float d2 = __uint_as_float(rv.y << 16);
    float d3 = __uint_as_float(rv.y & 0xffff0000u);
    float4 asv = *(const float4*)(a_src + (lane << 2));
    float4 adv = *(const float4*)(a_dst + (lane << 2));
    float as = d0 * asv.x + d1 * asv.y + d2 * asv.z + d3 * asv.w;
    float ad = d0 * adv.x + d1 * adv.y + d2 * adv.z + d3 * adv.w;
#pragma unroll
    for (int off = 32; off; off >>= 1) {
        as += __shfl_down(as, off);
        ad += __shfl_down(ad, off);
    }
    if (lane == 0) { s_src[node] = as; s_dst[node] = ad; }
}

__device__ __forceinline__ void atomicMaxFloat(float* addr, float val)
{
    int* ai = (int*)addr;
    int old = __float_as_int(*addr);
    while (__int_as_float(old) < val) {
        int prev = atomicCAS(ai, old, __float_as_int(val));
        if (prev == old) break;
        old = prev;
    }
}

__global__ void edge_pass1(const int* __restrict__ ei, const float* __restrict__ s_src,
                           const float* __restrict__ s_dst, float* __restrict__ e_buf,
                           float* __restrict__ emax, int* __restrict__ deg)
{
    int j = blockIdx.x * 256 + threadIdx.x;
    if (j >= EE_EDGES) return;
    int s, d;
    if (j < E_EDGES) { s = ei[j]; d = ei[E_EDGES + j]; }
    else { s = d = j - E_EDGES; }
    float e = s_src[s] + s_dst[d];
    e = (e > 0.f) ? e : 0.2f * e;
    e_buf[j] = e;
    atomicMaxFloat(&emax[d], e);
    atomicAdd(&deg[d], 1);
}

__global__ void scan1(const int* __restrict__ in, int* __restrict__ out_excl,
                      int* __restrict__ bsum)
{
    __shared__ int s[256];
    int t = threadIdx.x;
    int i = blockIdx.x * 256 + t;
    int v = in[i];
    s[t] = v;
    __syncthreads();
    for (int off = 1; off < 256; off <<= 1) {
        int u = (t >= off) ? s[t - off] : 0;
        __syncthreads();
        s[t] += u;
        __syncthreads();
    }
    out_excl[i] = s[t] - v;
    if (t == 255) bsum[blockIdx.x] = s[255];
}

__global__ void scan2(int* __restrict__ bsum)
{
    __shared__ int s[256];
    int t = threadIdx.x;
    int v = bsum[t];
    s[t] = v;
    __syncthreads();
    for (int off = 1; off < 256; off <<= 1) {
        int u = (t >= off) ? s[t - off] : 0;
        __syncthreads();
        s[t] += u;
        __syncthreads();
    }
    bsum[t] = s[t] - v;
}

__global__ void scan3(int* __restrict__ offs, const int* __restrict__ bsum,
                      int* __restrict__ cur)
{
    int i = blockIdx.x * 256 + threadIdx.x;
    int v = offs[i] + bsum[blockIdx.x];
    offs[i] = v;
    cur[i] = v;
}

__global__ void edge_pass2(const int* __restrict__ ei, const float* __restrict__ e_buf,
                           const float* __restrict__ emax, float* __restrict__ denom,
                           int* __restrict__ cur, int* __restrict__ csr_src,
                           float* __restrict__ csr_w)
{
    int j = blockIdx.x * 256 + threadIdx.x;
    if (j >= EE_EDGES) return;
    int s, d;
    if (j < E_EDGES) { s = ei[j]; d = ei[E_EDGES + j]; }
    else { s = d = j - E_EDGES; }
    float ee = __expf(e_buf[j] - emax[d]);
    atomicAdd(&denom[d], ee);
    int pos = atomicAdd(&cur[d], 1);
    csr_src[pos] = s;
    csr_w[pos] = ee;
}

// bf16 WH gather; writes h as bf16 hi/lo for the embedding GEMM (APRE).
__global__ __launch_bounds__(256) void gat_aggregate(
    const u16* __restrict__ WH, const int* __restrict__ csr_src,
    const float* __restrict__ csr_w, const int* __restrict__ offs,
    const int* __restrict__ deg, const float* __restrict__ denom,
    const float* __restrict__ b_gat, u16* __restrict__ hH, u16* __restrict__ hL)
{
    int gid = blockIdx.x * 256 + threadIdx.x;
    int node = gid >> 6;
    int lane = gid & 63;
    float inv = 1.0f / denom[node];
    float a0 = 0.f, a1 = 0.f, a2 = 0.f, a3 = 0.f;
    int s0 = offs[node], e0 = s0 + deg[node];
    for (int k = s0; k < e0; ++k) {
        int src = csr_src[k];
        float alpha = csr_w[k] * inv;
        uint2 rv = *(const uint2*)(WH + (size_t)src * D_MODEL + (lane << 2));
        a0 += alpha * __uint_as_float(rv.x << 16);
        a1 += alpha * __uint_as_float(rv.x & 0xffff0000u);
        a2 += alpha * __uint_as_float(rv.y << 16);
        a3 += alpha * __uint_as_float(rv.y & 0xffff0000u);
    }
    float4 bg = *(const float4*)(b_gat + (lane << 2));
    float v0 = a0 + bg.x, v1 = a1 + bg.y, v2 = a2 + bg.z, v3 = a3 + bg.w;
    u16 h0 = f2bf(v0), h1 = f2bf(v1), h2 = f2bf(v2), h3 = f2bf(v3);
    uint2 ho, lo;
    ho.x = (unsigned)h0 | ((unsigned)h1 << 16);
    ho.y = (unsigned)h2 | ((unsigned)h3 << 16);
    lo.x = (unsigned)f2bf(v0 - bf2f(h0)) | ((unsigned)f2bf(v1 - bf2f(h1)) << 16);
    lo.y = (unsigned)f2bf(v2 - bf2f(h2)) | ((unsigned)f2bf(v3 - bf2f(h3)) << 16);
    size_t base = (size_t)node * D_MODEL + (lane << 2);
    *(uint2*)(hH + base) = ho;
    *(uint2*)(hL + base) = lo;
}

// ---------------------------------------------------------------------------
// LayerNorm: reads seqio row, writes Yh/Yl (bf16 split) and folds the NEXT
// GEMM's bias into seqio in place (residual preadd for the ATOM path).
// ---------------------------------------------------------------------------
__global__ __launch_bounds__(256) void ln_kernel(
    float* __restrict__ seqio, const float* __restrict__ sc,
    const float* __restrict__ bi, u16* __restrict__ Yh, u16* __restrict__ Yl,
    const float* __restrict__ badd)
{
    int row = blockIdx.x;
    int t = threadIdx.x;
    float x = seqio[(size_t)row * 256 + t];
    float sum = x, sq = x * x;
#pragma unroll
    for (int off = 32; off; off >>= 1) {
        sum += __shfl_down(sum, off);
        sq  += __shfl_down(sq, off);
    }
    __shared__ float rs[4], rq[4];
    if ((t & 63) == 0) { rs[t >> 6] = sum; rq[t >> 6] = sq; }
    __syncthreads();
    sum = rs[0] + rs[1] + rs[2] + rs[3];
    sq  = rq[0] + rq[1] + rq[2] + rq[3];
    float mean = sum * (1.f / 256.f);
    float var  = sq * (1.f / 256.f) - mean * mean;
    float r = rsqrtf(var + 1e-5f);
    float y = (x - mean) * r * sc[t] + bi[t];
    u16 h = f2bf(y);
    Yh[(size_t)row * 256 + t] = h;
    Yl[(size_t)row * 256 + t] = f2bf(y - bf2f(h));
    seqio[(size_t)row * 256 + t] = x + badd[t];
}

// ---------------------------------------------------------------------------
// MFMA flash attention (as round 3) — epilogue now writes bf16 hi/lo.
// ---------------------------------------------------------------------------
__global__ __launch_bounds__(256) void mfma_attn(
    const u16* __restrict__ QKV, u16* __restrict__ Oh, u16* __restrict__ Ol)
{
    __shared__ __align__(16) u16 Ks[64 * 32];
    __shared__ __align__(16) u16 Vt[32 * 72];
    __shared__ __align__(16) u16 Ps[4 * 16 * 72];
    const int tid = threadIdx.x;
    const int w = tid >> 6, lane = tid & 63;
    const int g = lane >> 4, ql = lane & 15;
    const int h = blockIdx.y;
    const int qbase = blockIdx.x * 64 + w * 16;
    const float scale = 0.17677669529663687f;

    int qrow = qbase + ql; if (qrow > SEQ_LEN - 1) qrow = SEQ_LEN - 1;
    const s8v qfrag = *(const s8v*)(QKV + (size_t)qrow * 768 + h * 32 + g * 8);

    f4v o0 = {0.f, 0.f, 0.f, 0.f}, o1 = o0;
    float m[4], l[4];
#pragma unroll
    for (int r = 0; r < 4; ++r) { m[r] = -1e30f; l[r] = 0.f; }

    const int sr = tid >> 2, sc_ = tid & 3;
    const int kslot = sc_ ^ ((sr >> 1) & 3);
    u16* const psw = &Ps[w * 1152];

    for (int t = 0; t < 33; ++t) {
        __syncthreads();
        {
            int grow = t * 64 + sr;
            const u16* kp = QKV + (size_t)grow * 768 + 256 + h * 32 + sc_ * 8;
            s8v kvv = *(const s8v*)kp;
            s8v vvv = *(const s8v*)(kp + 256);
            *(s8v*)&Ks[sr * 32 + kslot * 8] = kvv;
#pragma unroll
            for (int e = 0; e < 8; ++e) Vt[(sc_ * 8 + e) * 72 + sr] = (u16)vvv[e];
        }
        __syncthreads();

        f4v s[4];
        const f4v zz = {0.f, 0.f, 0.f, 0.f};
#pragma unroll
        for (int c = 0; c < 4; ++c) {
            int kvloc = c * 16 + ql;
            s8v kf = *(s8v*)&Ks[kvloc * 32 + ((g ^ ((kvloc >> 1) & 3)) << 3)];
            s[c] = __builtin_amdgcn_mfma_f32_16x16x32_bf16(qfrag, kf, zz, 0, 0, 0);
            int kvg = t * 64 + kvloc;
            bool valid = (kvg < SEQ_LEN);
#pragma unroll
            for (int r = 0; r < 4; ++r)
                s[c][r] = valid ? s[c][r] * scale : -1e30f;
        }

        float mloc[4];
#pragma unroll
        for (int r = 0; r < 4; ++r) {
            float v = fmaxf(fmaxf(s[0][r], s[1][r]), fmaxf(s[2][r], s[3][r]));
            v = fmaxf(v, __shfl_xor(v, 1));
            v = fmaxf(v, __shfl_xor(v, 2));
            v = fmaxf(v, __shfl_xor(v, 4));
            v = fmaxf(v, __shfl_xor(v, 8));
            mloc[r] = v;
        }
        float fac[4];
#pragma unroll
        for (int r = 0; r < 4; ++r) {
            float mn = fmaxf(m[r], mloc[r]);
            fac[r] = __expf(m[r] - mn);
            m[r] = mn;
        }
#pragma unroll
        for (int c = 0; c < 4; ++c)
#pragma unroll
            for (int r = 0; r < 4; ++r)
                s[c][r] = __expf(s[c][r] - m[r]);
#pragma unroll
        for (int r = 0; r < 4; ++r) {
            float ls = s[0][r] + s[1][r] + s[2][r] + s[3][r];
            ls += __shfl_xor(ls, 1);
            ls += __shfl_xor(ls, 2);
            ls += __shfl_xor(ls, 4);
            ls += __shfl_xor(ls, 8);
            l[r] = l[r] * fac[r] + ls;
            o0[r] *= fac[r];
            o1[r] *= fac[r];
        }

#pragma unroll
        for (int c = 0; c < 4; ++c)
#pragma unroll
            for (int r = 0; r < 4; ++r)
                psw[(g * 4 + r) * 72 + c * 16 + ql] = f2bf(s[c][r]);

#pragma unroll
        for (int kch = 0; kch < 2; ++kch) {
            s8v pf = *(s8v*)&psw[ql * 72 + kch * 32 + g * 8];
            s8v v0 = *(s8v*)&Vt[ql * 72 + kch * 32 + g * 8];
            s8v v1 = *(s8v*)&Vt[(16 + ql) * 72 + kch * 32 + g * 8];
            o0 = __builtin_amdgcn_mfma_f32_16x16x32_bf16(pf, v0, o0, 0, 0, 0);
            o1 = __builtin_amdgcn_mfma_f32_16x16x32_bf16(pf, v1, o1, 0, 0, 0);
        }
    }

#pragma unroll
    for (int r = 0; r < 4; ++r) {
        int q = qbase + g * 4 + r;
        if (q < SEQ_LEN) {
            float invl = 1.f / l[r];
            size_t base = (size_t)q * 256 + h * 32;
            float v0 = o0[r] * invl, v1 = o1[r] * invl;
            u16 h0 = f2bf(v0), h1 = f2bf(v1);
            Oh[base + ql] = h0;
            Ol[base + ql] = f2bf(v0 - bf2f(h0));
            Oh[base + 16 + ql] = h1;
            Ol[base + 16 + ql] = f2bf(v1 - bf2f(h1));
        }
    }
}

__global__ void seed_seq(const float* __restrict__ cls, float* __restrict__ seq)
{
    seq[threadIdx.x] = cls[threadIdx.x];
}

__global__ void cls_head(const float* __restrict__ seq, const float* __restrict__ W,
                         const float* __restrict__ b, float* __restrict__ out)
{
    __shared__ float s[256];
    int t = threadIdx.x;
    s[t] = seq[t];
    __syncthreads();
    if (t < NCLS) {
        float acc = b[t];
        for (int k = 0; k < 256; ++k) acc += s[k] * W[k * NCLS + t];
        out[t] = acc;
    }
}

// ---------------------------------------------------------------------------
extern "C" void kernel_launch(void* const* d_in, const int* in_sizes, int n_in,
                              void* d_out, int out_size, void* d_ws, size_t ws_size,
                              hipStream_t stream)
{
    (void)in_sizes; (void)n_in; (void)out_size; (void)ws_size;
    const float* x       = (const float*)d_in[0];
    const int*   ei      = (const int*)d_in[1];
    const float* W_in    = (const float*)d_in[2];
    const float* b_in    = (const float*)d_in[3];
    const float* W_gat   = (const float*)d_in[4];
    const float* a_src   = (const float*)d_in[5];
    const float* a_dst   = (const float*)d_in[6];
    const float* b_gat   = (const float*)d_in[7];
    const float* W_emb   = (const float*)d_in[8];
    const float* b_emb   = (const float*)d_in[9];
    const float* cls_tok = (const float*)d_in[10];
    const float* ln1_s   = (const float*)d_in[11];
    const float* ln1_b   = (const float*)d_in[12];
    const float* Wqkv    = (const float*)d_in[13];
    const float* bqkv    = (const float*)d_in[14];
    const float* Wproj   = (const float*)d_in[15];
    const float* bproj   = (const float*)d_in[16];
    const float* ln2_s   = (const float*)d_in[17];
    const float* ln2_b   = (const float*)d_in[18];
    const float* W1      = (const float*)d_in[19];
    const float* b1      = (const float*)d_in[20];
    const float* W2      = (const float*)d_in[21];
    const float* b2      = (const float*)d_in[22];
    const float* W_cls   = (const float*)d_in[23];
    const float* b_cls   = (const float*)d_in[24];
    float* out = (float*)d_out;

    // -------- workspace layout --------
    float* ws = (float*)d_ws;
    // region A [0, 16777216 floats): WH (u16) during GAT; transformer after
    u16*   bufWHu = (u16*)ws;                  // 16777216 u16 (N x 256 bf16)
    float* seqb  = ws;                         // 524544 f
    u16*   Yh    = (u16*)(ws + 524544);        // 524544 u16
    u16*   Yl    = Yh + 524544;
    u16*   QKVb  = (u16*)(ws + 1049088);       // 2112*768 u16
    u16*   Oh    = (u16*)(ws + 1860096);       // 524544 u16
    u16*   Ol    = Oh + 524544;
    u16*   MLPHh = (u16*)(ws + 2384640);       // 2049*1024 u16
    u16*   MLPHl = MLPHh + 2098176;            // ends @ 3433728+1049088 f
    u16*   wreg  = (u16*)(ws + 5500000);       // weights, ends @ 13888608 f
    u16* embh  = wreg;
    u16* embl  = wreg + 2097152;
    u16* qkvh  = wreg + 4194304;
    u16* qkvl  = wreg + 5767168;
    u16* projh = wreg + 7340032;
    u16* projl = wreg + 7864320;
    u16* w1h   = wreg + 8388608;
    u16* w1l   = wreg + 10485760;
    u16* w2h   = wreg + 12582912;
    u16* w2l   = wreg + 14680064;
    // region B [16777216, 33554432): GAT output h as bf16 hi/lo
    u16* hH = (u16*)(ws + 16777216);           // 16777216 u16
    u16* hL = hH + 16777216;
    // region C: graph scratch
    float* sm    = ws + 2 * 16777216;
    float* s_src = sm;
    float* s_dst = sm + 65536;
    float* emaxb = sm + 2 * 65536;
    float* denom = sm + 3 * 65536;
    float* e_buf = sm + 4 * 65536;
    float* csr_w = e_buf + 589824;
    float* Wc    = csr_w + 589824;
    float* bc    = Wc + 32768;
    int*   deg     = (int*)(bc + 256);
    int*   offs    = deg + 65536;
    int*   cur     = offs + 65536;
    int*   bsum    = cur + 65536;
    int*   csr_src = bsum + 256;
    u16*   wgTh = (u16*)(csr_src + 589824);
    u16*   wgTl = wgTh + 65536;
    u16*   wcTh = wgTh + 131072;
    u16*   wcTl = wcTh + 32768;

    // -------- GAT preprocessing --------
    gat_init<<<256, 256, 0, stream>>>(emaxb, denom, deg);
    prep_weight<<<dim3(4, 4, 1), 256, 0, stream>>>(W_gat, wgTh, wgTl, 256, 256, 0, 0);
    hgemm<0,0,0,0,0><<<dim3(4, 2, 1), 256, 0, stream>>>(
        W_in, nullptr, wgTh, wgTl, nullptr, nullptr, Wc, nullptr, 128, 256, 256, 256);
    vecmat256<<<1, 256, 0, stream>>>(b_in, W_gat, bc);
    prep_weight<<<dim3(2, 4, 1), 256, 0, stream>>>(Wc, wcTh, wcTl, 128, 256, 0, 0);
    // WH = x @ Wc + bc  (bf16 output)
    hgemm<0,0,0,1,0><<<dim3(4, 1024, 1), 256, 0, stream>>>(
        x, nullptr, wcTh, wcTl, bc, nullptr, (float*)bufWHu, nullptr,
        N_NODES, 256, 128, 128);
    gat_scores<<<16384, 256, 0, stream>>>(bufWHu, a_src, a_dst, s_src, s_dst);
    edge_pass1<<<EE_EDGES / 256, 256, 0, stream>>>(ei, s_src, s_dst, e_buf, emaxb, deg);
    scan1<<<256, 256, 0, stream>>>(deg, offs, bsum);
    scan2<<<1, 256, 0, stream>>>(bsum);
    scan3<<<256, 256, 0, stream>>>(offs, bsum, cur);
    edge_pass2<<<EE_EDGES / 256, 256, 0, stream>>>(ei, e_buf, emaxb, denom, cur,
                                                   csr_src, csr_w);
    gat_aggregate<<<16384, 256, 0, stream>>>(bufWHu, csr_src, csr_w, offs, deg,
                                             denom, b_gat, hH, hL);

    // -------- weight prep (region A WH dead now) --------
    prep_weight<<<dim3(128, 4, 1), 256, 0, stream>>>(W_emb, embh, embl, 8192, 256, 0, 0);
    prep_weight<<<dim3(4, 12, 8), 256, 0, stream>>>(Wqkv, qkvh, qkvl, 256, 768,
                                                    196608, 196608);
    prep_weight<<<dim3(4, 4, 8), 256, 0, stream>>>(Wproj, projh, projl, 256, 256,
                                                   65536, 65536);
    prep_weight<<<dim3(4, 16, 8), 256, 0, stream>>>(W1, w1h, w1l, 256, 1024,
                                                    262144, 262144);
    prep_weight<<<dim3(16, 4, 8), 256, 0, stream>>>(W2, w2h, w2l, 1024, 256,
                                                    262144, 262144);

    // -------- token embedding (split-K x8, atomic, A pre-split) --------
    init_bias<<<2048, 256, 0, stream>>>(seqb + 256, b_emb, 2048 * 256, 255);
    hgemm<0,0,1,0,1><<<dim3(4, 32, 8), 256, 0, stream>>>(
        (const void*)hH, hL, embh, embl, nullptr, nullptr, seqb + 256, nullptr,
        2048, 256, 8192, 1024);
    seed_seq<<<1, 256, 0, stream>>>(cls_tok, seqb);

    pad_zero_u32<<<95, 256, 0, stream>>>(
        (unsigned*)(QKVb + (size_t)SEQ_LEN * 768), (SEQ_PAD - SEQ_LEN) * 768 / 2);

    // -------- transformer layers --------
    for (int i = 0; i < 8; ++i) {
        // ln1: Y = LN(seq); seq += bproj (preadd for proj ATOM)
        ln_kernel<<<SEQ_LEN, 256, 0, stream>>>(seqb, ln1_s + i * 256,
                                               ln1_b + i * 256, Yh, Yl,
                                               bproj + i * 256);
        hgemm<0,0,0,1,1><<<dim3(12, 33, 1), 256, 0, stream>>>(
            (const void*)Yh, Yl, qkvh + (size_t)i * 196608, qkvl + (size_t)i * 196608,
            bqkv + i * 768, nullptr, (float*)QKVb, nullptr, SEQ_LEN, 768, 256, 256);
        mfma_attn<<<dim3(33, NHEAD), 256, 0, stream>>>(QKVb, Oh, Ol);
        // proj: split-K x4, atomic into seqb (residual+bias already there)
        hgemm<0,0,1,0,1><<<dim3(4, 33, 4), 256, 0, stream>>>(
            (const void*)Oh, Ol, projh + (size_t)i * 65536, projl + (size_t)i * 65536,
            nullptr, nullptr, seqb, nullptr, SEQ_LEN, 256, 256, 64);
        // ln2: Y = LN(seq); seq += b2 (preadd for mlp2 ATOM)
        ln_kernel<<<SEQ_LEN, 256, 0, stream>>>(seqb, ln2_s + i * 256,
                                               ln2_b + i * 256, Yh, Yl,
                                               b2 + i * 256);
        hgemm<1,0,0,2,1><<<dim3(16, 33, 1), 256, 0, stream>>>(
            (const void*)Yh, Yl, w1h + (size_t)i * 262144, w1l + (size_t)i * 262144,
            b1 + i * 1024, nullptr, (float*)MLPHh, MLPHl, SEQ_LEN, 1024, 256, 256);
        // mlp2: split-K x4, atomic into seqb
        hgemm<0,0,1,0,1><<<dim3(4, 33, 4), 256, 0, stream>>>(
            (const void*)MLPHh, MLPHl, w2h + (size_t)i * 262144, w2l + (size_t)i * 262144,
            nullptr, nullptr, seqb, nullptr, SEQ_LEN, 256, 1024, 256);
    }

    // -------- classifier head --------
    cls_head<<<1, 256, 0, stream>>>(seqb, W_cls, b_cls, out);
}

// Round 5
// 1214.800 us; speedup vs baseline: 4.7066x; 1.1001x over previous
//
#include <hip/hip_runtime.h>
#include <math.h>

#define N_NODES 65536
#define F_IN 128
#define D_MODEL 256
#define E_EDGES 524288
#define EE_EDGES 589824   /* E + N self loops */
#define SEQ_LEN 2049
#define SEQ_PAD 2112      /* 33*64 */
#define NHEAD 8
#define HDIM 32
#define NCLS 10

typedef unsigned short u16;
typedef __attribute__((ext_vector_type(8))) short s8v;   // 8 x bf16 (4 VGPR)
typedef __attribute__((ext_vector_type(4))) float f4v;   // 4 x f32 acc

__device__ __forceinline__ u16 f2bf(float f)
{
    union { float f; unsigned u; } v; v.f = f;
    unsigned r = v.u + 0x7FFF + ((v.u >> 16) & 1);
    return (u16)(r >> 16);
}
__device__ __forceinline__ float bf2f(u16 h)
{
    union { unsigned u; float f; } v; v.u = ((unsigned)h) << 16;
    return v.f;
}

// ---------------------------------------------------------------------------
// prep: W [K,N] fp32 (row-major) -> Oh (and optionally Ol) [N,K] bf16
// ---------------------------------------------------------------------------
__global__ __launch_bounds__(256) void prep_weight(
    const float* __restrict__ W, u16* __restrict__ Oh, u16* __restrict__ Ol,
    int K, int N, long long strideW, long long strideO, int write_lo)
{
    const float* Wz = W + (size_t)blockIdx.z * strideW;
    u16* Ohz = Oh + (size_t)blockIdx.z * strideO;
    u16* Olz = Ol + (size_t)blockIdx.z * strideO;
    __shared__ u16 th[64][68];
    __shared__ u16 tl[64][68];
    int kb = blockIdx.x * 64, nb = blockIdx.y * 64;
    int t = threadIdx.x;
    int kr = t >> 4, nc = (t & 15) * 4;
#pragma unroll
    for (int i = 0; i < 4; ++i) {
        int k = kr + i * 16;
        float4 v = *(const float4*)(Wz + (size_t)(kb + k) * N + nb + nc);
        float vv[4] = {v.x, v.y, v.z, v.w};
#pragma unroll
        for (int e = 0; e < 4; ++e) {
            u16 h = f2bf(vv[e]);
            th[k][nc + e] = h;
            if (write_lo) tl[k][nc + e] = f2bf(vv[e] - bf2f(h));
        }
    }
    __syncthreads();
    int nr = t >> 4, kc = (t & 15) * 4;
#pragma unroll
    for (int i = 0; i < 4; ++i) {
        int n = nr + i * 16;
        uint2 oh;
        oh.x = (unsigned)th[kc + 0][n] | ((unsigned)th[kc + 1][n] << 16);
        oh.y = (unsigned)th[kc + 2][n] | ((unsigned)th[kc + 3][n] << 16);
        *(uint2*)(Ohz + (size_t)(nb + n) * K + kb + kc) = oh;
        if (write_lo) {
            uint2 ol;
            ol.x = (unsigned)tl[kc + 0][n] | ((unsigned)tl[kc + 1][n] << 16);
            ol.y = (unsigned)tl[kc + 2][n] | ((unsigned)tl[kc + 3][n] << 16);
            *(uint2*)(Olz + (size_t)(nb + n) * K + kb + kc) = ol;
        }
    }
}

// ---------------------------------------------------------------------------
// bf16 MFMA GEMM. TERMS=3: split hi/lo 3-term (~fp32); TERMS=1: plain bf16.
// APRE=0: A fp32 (converted in-kernel). APRE=1: A bf16 (Al2 = lo if TERMS=3).
// OB: 0 fp32 C; 1 bf16 C. ATOM=1: fp32 atomicAdd into preinited C.
// ---------------------------------------------------------------------------
template<int ACT, int RES, int ATOM, int OB, int APRE, int TERMS>
__global__ __launch_bounds__(256) void hgemm(
    const void* __restrict__ A, const u16* __restrict__ Al2,
    const u16* __restrict__ Bh, const u16* __restrict__ Bl,
    const float* __restrict__ bias, const float* __restrict__ Rsd,
    float* __restrict__ C, u16* __restrict__ C2,
    int M, int N, int K, int Kc)
{
    __shared__ __align__(16) u16 SS[(TERMS == 3 ? 4 : 2) * 2048];
    u16* const AhS = SS;
    u16* const BhS = SS + 2048;
    u16* const AlS = SS + 4096;   // TERMS==3 only
    u16* const BlS = SS + 6144;
    const int tid = threadIdx.x;
    const int bn = blockIdx.x * 64, bm = blockIdx.y * 64;
    const int kb = blockIdx.z * Kc;
    const int r = tid >> 2, cch = tid & 3;
    const int widx = r * 32 + ((cch ^ ((r >> 1) & 3)) << 3);
    const int w = tid >> 6, lane = tid & 63;
    const int wm = w >> 1, wn = w & 1;
    const int lr = lane & 15, lc = lane >> 4;
    const int ar0 = wm * 32 + lr, ar1 = ar0 + 16;
    const int nr0 = wn * 32 + lr, nr1 = nr0 + 16;
    const int ai0 = ar0 * 32 + ((lc ^ ((ar0 >> 1) & 3)) << 3);
    const int ai1 = ar1 * 32 + ((lc ^ ((ar1 >> 1) & 3)) << 3);
    const int bi0 = nr0 * 32 + ((lc ^ ((nr0 >> 1) & 3)) << 3);
    const int bi1 = nr1 * 32 + ((lc ^ ((nr1 >> 1) & 3)) << 3);

    f4v acc00 = {0.f, 0.f, 0.f, 0.f}, acc01 = acc00, acc10 = acc00, acc11 = acc00;

    const int gr = bm + r;
    const float* apf = (const float*)A + (size_t)gr * K + kb + cch * 8;
    const u16*   aph = (const u16*)A + (size_t)gr * K + kb + cch * 8;
    const u16*   apl = Al2 ? Al2 + (size_t)gr * K + kb + cch * 8 : (const u16*)0;
    const u16* bhp = Bh + (size_t)(bn + r) * K + kb + cch * 8;
    const u16* blp = (TERMS == 3) ? Bl + (size_t)(bn + r) * K + kb + cch * 8
                                  : (const u16*)0;

    for (int k0 = 0; k0 < Kc; k0 += 32) {
        s8v hv = {0, 0, 0, 0, 0, 0, 0, 0}, lv = hv;
        if (APRE) {
            if (gr < M) {
                hv = *(const s8v*)aph;
                if (TERMS == 3) lv = *(const s8v*)apl;
            }
        } else {
            float v[8] = {0.f, 0.f, 0.f, 0.f, 0.f, 0.f, 0.f, 0.f};
            if (gr < M) {
                float4 x0 = *(const float4*)apf;
                float4 x1 = *(const float4*)(apf + 4);
                v[0] = x0.x; v[1] = x0.y; v[2] = x0.z; v[3] = x0.w;
                v[4] = x1.x; v[5] = x1.y; v[6] = x1.z; v[7] = x1.w;
            }
#pragma unroll
            for (int e = 0; e < 8; ++e) {
                u16 h = f2bf(v[e]);
                hv[e] = (short)h;
                if (TERMS == 3) lv[e] = (short)f2bf(v[e] - bf2f(h));
            }
        }
        *(s8v*)&AhS[widx] = hv;
        *(s8v*)&BhS[widx] = *(const s8v*)bhp;
        if (TERMS == 3) {
            *(s8v*)&AlS[widx] = lv;
            *(s8v*)&BlS[widx] = *(const s8v*)blp;
        }
        __syncthreads();

        s8v a0h = *(s8v*)&AhS[ai0], a1h = *(s8v*)&AhS[ai1];
        s8v b0h = *(s8v*)&BhS[bi0], b1h = *(s8v*)&BhS[bi1];
        acc00 = __builtin_amdgcn_mfma_f32_16x16x32_bf16(a0h, b0h, acc00, 0, 0, 0);
        acc01 = __builtin_amdgcn_mfma_f32_16x16x32_bf16(a0h, b1h, acc01, 0, 0, 0);
        acc10 = __builtin_amdgcn_mfma_f32_16x16x32_bf16(a1h, b0h, acc10, 0, 0, 0);
        acc11 = __builtin_amdgcn_mfma_f32_16x16x32_bf16(a1h, b1h, acc11, 0, 0, 0);
        if (TERMS == 3) {
            s8v a0l = *(s8v*)&AlS[ai0], a1l = *(s8v*)&AlS[ai1];
            s8v b0l = *(s8v*)&BlS[bi0], b1l = *(s8v*)&BlS[bi1];
            acc00 = __builtin_amdgcn_mfma_f32_16x16x32_bf16(a0h, b0l, acc00, 0, 0, 0);
            acc00 = __builtin_amdgcn_mfma_f32_16x16x32_bf16(a0l, b0h, acc00, 0, 0, 0);
            acc01 = __builtin_amdgcn_mfma_f32_16x16x32_bf16(a0h, b1l, acc01, 0, 0, 0);
            acc01 = __builtin_amdgcn_mfma_f32_16x16x32_bf16(a0l, b1h, acc01, 0, 0, 0);
            acc10 = __builtin_amdgcn_mfma_f32_16x16x32_bf16(a1h, b0l, acc10, 0, 0, 0);
            acc10 = __builtin_amdgcn_mfma_f32_16x16x32_bf16(a1l, b0h, acc10, 0, 0, 0);
            acc11 = __builtin_amdgcn_mfma_f32_16x16x32_bf16(a1h, b1l, acc11, 0, 0, 0);
            acc11 = __builtin_amdgcn_mfma_f32_16x16x32_bf16(a1l, b1h, acc11, 0, 0, 0);
        }
        __syncthreads();
        apf += 32; aph += 32; if (TERMS == 3) apl += 32;
        bhp += 32; if (TERMS == 3) blp += 32;
    }

#pragma unroll
    for (int fg = 0; fg < 4; ++fg) {
        int f = fg >> 1, g = fg & 1;
        f4v a = (fg == 0) ? acc00 : (fg == 1) ? acc01 : (fg == 2) ? acc10 : acc11;
        int col = bn + wn * 32 + g * 16 + lr;
        int row0 = bm + wm * 32 + f * 16 + lc * 4;
#pragma unroll
        for (int j = 0; j < 4; ++j) {
            int rr = row0 + j;
            if (rr < M) {
                float vv = a[j];
                if (ATOM) {
                    atomicAdd(&C[(size_t)rr * N + col], vv);
                } else {
                    if (bias) vv += bias[col];
                    if (ACT == 1) vv = 0.5f * vv * (1.0f + erff(vv * 0.70710678118654752f));
                    if (RES) vv += Rsd[(size_t)rr * N + col];
                    if (OB == 1) ((u16*)C)[(size_t)rr * N + col] = f2bf(vv);
                    else         C[(size_t)rr * N + col] = vv;
                }
            }
        }
    }
    (void)C2;
}

__global__ void init_bias(float* __restrict__ C, const float* __restrict__ bias,
                          int total, int nmask)
{
    int i = blockIdx.x * 256 + threadIdx.x;
    if (i < total) C[i] = bias[i & nmask];
}

__global__ void pad_zero_u32(unsigned* __restrict__ p, int n)
{
    int i = blockIdx.x * 256 + threadIdx.x;
    if (i < n) p[i] = 0u;
}

__global__ void vecmat256(const float* __restrict__ v, const float* __restrict__ W,
                          float* __restrict__ out)
{
    int n = threadIdx.x;
    float acc = 0.f;
    for (int k = 0; k < 256; ++k) acc += v[k] * W[k * 256 + n];
    out[n] = acc;
}

// ---------------------------------------------------------------------------
// GAT pieces
// ---------------------------------------------------------------------------
__global__ void gat_init(float* __restrict__ emax, float* __restrict__ denom,
                         int* __restrict__ deg)
{
    int i = blockIdx.x * 256 + threadIdx.x;
    emax[i] = -1e30f;
    denom[i] = 0.f;
    deg[i] = 0;
}

__global__ __launch_bounds__(256) void gat_scores(
    const u16* __restrict__ WH, const float* __restrict__ a_src,
    const float* __restrict__ a_dst, float* __restrict__ s_src,
    float* __restrict__ s_dst)
{
    int gid = blockIdx.x * 256 + threadIdx.x;
    int node = gid >> 6;
    int lane = gid & 63;
    uint2 rv = *(const uint2*)(WH + (size_t)node * D_MODEL + (lane << 2));
    float d0 = __uint_as_float(rv.x << 16);
    float d1 = __uint_as_float(rv.x & 0xffff0000u);
    float d2 = __uint_as_float(rv.y << 16);
    float d3 = __uint_as_float(rv.y & 0xffff0000u);
    float4 asv = *(const float4*)(a_src + (lane << 2));
    float4 adv = *(const float4*)(a_dst + (lane << 2));
    float as = d0 * asv.x + d1 * asv.y + d2 * asv.z + d3 * asv.w;
    float ad = d0 * adv.x + d1 * adv.y + d2 * adv.z + d3 * adv.w;
#pragma unroll
    for (int off = 32; off; off >>= 1) {
        as += __shfl_down(as, off);
        ad += __shfl_down(ad, off);
    }
    if (lane == 0) { s_src[node] = as; s_dst[node] = ad; }
}

__device__ __forceinline__ void atomicMaxFloat(float* addr, float val)
{
    int* ai = (int*)addr;
    int old = __float_as_int(*addr);
    while (__int_as_float(old) < val) {
        int prev = atomicCAS(ai, old, __float_as_int(val));
        if (prev == old) break;
        old = prev;
    }
}

__global__ void edge_pass1(const int* __restrict__ ei, const float* __restrict__ s_src,
                           const float* __restrict__ s_dst, float* __restrict__ e_buf,
                           float* __restrict__ emax, int* __restrict__ deg)
{
    int j = blockIdx.x * 256 + threadIdx.x;
    if (j >= EE_EDGES) return;
    int s, d;
    if (j < E_EDGES) { s = ei[j]; d = ei[E_EDGES + j]; }
    else { s = d = j - E_EDGES; }
    float e = s_src[s] + s_dst[d];
    e = (e > 0.f) ? e : 0.2f * e;
    e_buf[j] = e;
    atomicMaxFloat(&emax[d], e);
    atomicAdd(&deg[d], 1);
}

__global__ void scan1(const int* __restrict__ in, int* __restrict__ out_excl,
                      int* __restrict__ bsum)
{
    __shared__ int s[256];
    int t = threadIdx.x;
    int i = blockIdx.x * 256 + t;
    int v = in[i];
    s[t] = v;
    __syncthreads();
    for (int off = 1; off < 256; off <<= 1) {
        int u = (t >= off) ? s[t - off] : 0;
        __syncthreads();
        s[t] += u;
        __syncthreads();
    }
    out_excl[i] = s[t] - v;
    if (t == 255) bsum[blockIdx.x] = s[255];
}

__global__ void scan2(int* __restrict__ bsum)
{
    __shared__ int s[256];
    int t = threadIdx.x;
    int v = bsum[t];
    s[t] = v;
    __syncthreads();
    for (int off = 1; off < 256; off <<= 1) {
        int u = (t >= off) ? s[t - off] : 0;
        __syncthreads();
        s[t] += u;
        __syncthreads();
    }
    bsum[t] = s[t] - v;
}

__global__ void scan3(int* __restrict__ offs, const int* __restrict__ bsum,
                      int* __restrict__ cur)
{
    int i = blockIdx.x * 256 + threadIdx.x;
    int v = offs[i] + bsum[blockIdx.x];
    offs[i] = v;
    cur[i] = v;
}

__global__ void edge_pass2(const int* __restrict__ ei, const float* __restrict__ e_buf,
                           const float* __restrict__ emax, float* __restrict__ denom,
                           int* __restrict__ cur, int* __restrict__ csr_src,
                           float* __restrict__ csr_w)
{
    int j = blockIdx.x * 256 + threadIdx.x;
    if (j >= EE_EDGES) return;
    int s, d;
    if (j < E_EDGES) { s = ei[j]; d = ei[E_EDGES + j]; }
    else { s = d = j - E_EDGES; }
    float ee = __expf(e_buf[j] - emax[d]);
    atomicAdd(&denom[d], ee);
    int pos = atomicAdd(&cur[d], 1);
    csr_src[pos] = s;
    csr_w[pos] = ee;
}

// bf16 WH gather -> h bf16 (single)
__global__ __launch_bounds__(256) void gat_aggregate(
    const u16* __restrict__ WH, const int* __restrict__ csr_src,
    const float* __restrict__ csr_w, const int* __restrict__ offs,
    const int* __restrict__ deg, const float* __restrict__ denom,
    const float* __restrict__ b_gat, u16* __restrict__ hH)
{
    int gid = blockIdx.x * 256 + threadIdx.x;
    int node = gid >> 6;
    int lane = gid & 63;
    float inv = 1.0f / denom[node];
    float a0 = 0.f, a1 = 0.f, a2 = 0.f, a3 = 0.f;
    int s0 = offs[node], e0 = s0 + deg[node];
    for (int k = s0; k < e0; ++k) {
        int src = csr_src[k];
        float alpha = csr_w[k] * inv;
        uint2 rv = *(const uint2*)(WH + (size_t)src * D_MODEL + (lane << 2));
        a0 += alpha * __uint_as_float(rv.x << 16);
        a1 += alpha * __uint_as_float(rv.x & 0xffff0000u);
        a2 += alpha * __uint_as_float(rv.y << 16);
        a3 += alpha * __uint_as_float(rv.y & 0xffff0000u);
    }
    float4 bg = *(const float4*)(b_gat + (lane << 2));
    float v0 = a0 + bg.x, v1 = a1 + bg.y, v2 = a2 + bg.z, v3 = a3 + bg.w;
    uint2 ho;
    ho.x = (unsigned)f2bf(v0) | ((unsigned)f2bf(v1) << 16);
    ho.y = (unsigned)f2bf(v2) | ((unsigned)f2bf(v3) << 16);
    *(uint2*)(hH + (size_t)node * D_MODEL + (lane << 2)) = ho;
}

// ---------------------------------------------------------------------------
// LayerNorm: writes Yh (bf16) and folds next GEMM's bias into seqio in place.
// ---------------------------------------------------------------------------
__global__ __launch_bounds__(256) void ln_kernel(
    float* __restrict__ seqio, const float* __restrict__ sc,
    const float* __restrict__ bi, u16* __restrict__ Yh,
    const float* __restrict__ badd)
{
    int row = blockIdx.x;
    int t = threadIdx.x;
    float x = seqio[(size_t)row * 256 + t];
    float sum = x, sq = x * x;
#pragma unroll
    for (int off = 32; off; off >>= 1) {
        sum += __shfl_down(sum, off);
        sq  += __shfl_down(sq, off);
    }
    __shared__ float rs[4], rq[4];
    if ((t & 63) == 0) { rs[t >> 6] = sum; rq[t >> 6] = sq; }
    __syncthreads();
    sum = rs[0] + rs[1] + rs[2] + rs[3];
    sq  = rq[0] + rq[1] + rq[2] + rq[3];
    float mean = sum * (1.f / 256.f);
    float var  = sq * (1.f / 256.f) - mean * mean;
    float r = rsqrtf(var + 1e-5f);
    float y = (x - mean) * r * sc[t] + bi[t];
    Yh[(size_t)row * 256 + t] = f2bf(y);
    seqio[(size_t)row * 256 + t] = x + badd[t];
}

// ---------------------------------------------------------------------------
// MFMA flash attention — epilogue writes bf16 (single).
// ---------------------------------------------------------------------------
__global__ __launch_bounds__(256) void mfma_attn(
    const u16* __restrict__ QKV, u16* __restrict__ Oh)
{
    __shared__ __align__(16) u16 Ks[64 * 32];
    __shared__ __align__(16) u16 Vt[32 * 72];
    __shared__ __align__(16) u16 Ps[4 * 16 * 72];
    const int tid = threadIdx.x;
    const int w = tid >> 6, lane = tid & 63;
    const int g = lane >> 4, ql = lane & 15;
    const int h = blockIdx.y;
    const int qbase = blockIdx.x * 64 + w * 16;
    const float scale = 0.17677669529663687f;

    int qrow = qbase + ql; if (qrow > SEQ_LEN - 1) qrow = SEQ_LEN - 1;
    const s8v qfrag = *(const s8v*)(QKV + (size_t)qrow * 768 + h * 32 + g * 8);

    f4v o0 = {0.f, 0.f, 0.f, 0.f}, o1 = o0;
    float m[4], l[4];
#pragma unroll
    for (int r = 0; r < 4; ++r) { m[r] = -1e30f; l[r] = 0.f; }

    const int sr = tid >> 2, sc_ = tid & 3;
    const int kslot = sc_ ^ ((sr >> 1) & 3);
    u16* const psw = &Ps[w * 1152];

    for (int t = 0; t < 33; ++t) {
        __syncthreads();
        {
            int grow = t * 64 + sr;
            const u16* kp = QKV + (size_t)grow * 768 + 256 + h * 32 + sc_ * 8;
            s8v kvv = *(const s8v*)kp;
            s8v vvv = *(const s8v*)(kp + 256);
            *(s8v*)&Ks[sr * 32 + kslot * 8] = kvv;
#pragma unroll
            for (int e = 0; e < 8; ++e) Vt[(sc_ * 8 + e) * 72 + sr] = (u16)vvv[e];
        }
        __syncthreads();

        f4v s[4];
        const f4v zz = {0.f, 0.f, 0.f, 0.f};
#pragma unroll
        for (int c = 0; c < 4; ++c) {
            int kvloc = c * 16 + ql;
            s8v kf = *(s8v*)&Ks[kvloc * 32 + ((g ^ ((kvloc >> 1) & 3)) << 3)];
            s[c] = __builtin_amdgcn_mfma_f32_16x16x32_bf16(qfrag, kf, zz, 0, 0, 0);
            int kvg = t * 64 + kvloc;
            bool valid = (kvg < SEQ_LEN);
#pragma unroll
            for (int r = 0; r < 4; ++r)
                s[c][r] = valid ? s[c][r] * scale : -1e30f;
        }

        float mloc[4];
#pragma unroll
        for (int r = 0; r < 4; ++r) {
            float v = fmaxf(fmaxf(s[0][r], s[1][r]), fmaxf(s[2][r], s[3][r]));
            v = fmaxf(v, __shfl_xor(v, 1));
            v = fmaxf(v, __shfl_xor(v, 2));
            v = fmaxf(v, __shfl_xor(v, 4));
            v = fmaxf(v, __shfl_xor(v, 8));
            mloc[r] = v;
        }
        float fac[4];
#pragma unroll
        for (int r = 0; r < 4; ++r) {
            float mn = fmaxf(m[r], mloc[r]);
            fac[r] = __expf(m[r] - mn);
            m[r] = mn;
        }
#pragma unroll
        for (int c = 0; c < 4; ++c)
#pragma unroll
            for (int r = 0; r < 4; ++r)
                s[c][r] = __expf(s[c][r] - m[r]);
#pragma unroll
        for (int r = 0; r < 4; ++r) {
            float ls = s[0][r] + s[1][r] + s[2][r] + s[3][r];
            ls += __shfl_xor(ls, 1);
            ls += __shfl_xor(ls, 2);
            ls += __shfl_xor(ls, 4);
            ls += __shfl_xor(ls, 8);
            l[r] = l[r] * fac[r] + ls;
            o0[r] *= fac[r];
            o1[r] *= fac[r];
        }

#pragma unroll
        for (int c = 0; c < 4; ++c)
#pragma unroll
            for (int r = 0; r < 4; ++r)
                psw[(g * 4 + r) * 72 + c * 16 + ql] = f2bf(s[c][r]);

#pragma unroll
        for (int kch = 0; kch < 2; ++kch) {
            s8v pf = *(s8v*)&psw[ql * 72 + kch * 32 + g * 8];
            s8v v0 = *(s8v*)&Vt[ql * 72 + kch * 32 + g * 8];
            s8v v1 = *(s8v*)&Vt[(16 + ql) * 72 + kch * 32 + g * 8];
            o0 = __builtin_amdgcn_mfma_f32_16x16x32_bf16(pf, v0, o0, 0, 0, 0);
            o1 = __builtin_amdgcn_mfma_f32_16x16x32_bf16(pf, v1, o1, 0, 0, 0);
        }
    }

#pragma unroll
    for (int r = 0; r < 4; ++r) {
        int q = qbase + g * 4 + r;
        if (q < SEQ_LEN) {
            float invl = 1.f / l[r];
            size_t base = (size_t)q * 256 + h * 32;
            Oh[base + ql] = f2bf(o0[r] * invl);
            Oh[base + 16 + ql] = f2bf(o1[r] * invl);
        }
    }
}

__global__ void seed_seq(const float* __restrict__ cls, float* __restrict__ seq)
{
    seq[threadIdx.x] = cls[threadIdx.x];
}

__global__ void cls_head(const float* __restrict__ seq, const float* __restrict__ W,
                         const float* __restrict__ b, float* __restrict__ out)
{
    __shared__ float s[256];
    int t = threadIdx.x;
    s[t] = seq[t];
    __syncthreads();
    if (t < NCLS) {
        float acc = b[t];
        for (int k = 0; k < 256; ++k) acc += s[k] * W[k * NCLS + t];
        out[t] = acc;
    }
}

// ---------------------------------------------------------------------------
extern "C" void kernel_launch(void* const* d_in, const int* in_sizes, int n_in,
                              void* d_out, int out_size, void* d_ws, size_t ws_size,
                              hipStream_t stream)
{
    (void)in_sizes; (void)n_in; (void)out_size; (void)ws_size;
    const float* x       = (const float*)d_in[0];
    const int*   ei      = (const int*)d_in[1];
    const float* W_in    = (const float*)d_in[2];
    const float* b_in    = (const float*)d_in[3];
    const float* W_gat   = (const float*)d_in[4];
    const float* a_src   = (const float*)d_in[5];
    const float* a_dst   = (const float*)d_in[6];
    const float* b_gat   = (const float*)d_in[7];
    const float* W_emb   = (const float*)d_in[8];
    const float* b_emb   = (const float*)d_in[9];
    const float* cls_tok = (const float*)d_in[10];
    const float* ln1_s   = (const float*)d_in[11];
    const float* ln1_b   = (const float*)d_in[12];
    const float* Wqkv    = (const float*)d_in[13];
    const float* bqkv    = (const float*)d_in[14];
    const float* Wproj   = (const float*)d_in[15];
    const float* bproj   = (const float*)d_in[16];
    const float* ln2_s   = (const float*)d_in[17];
    const float* ln2_b   = (const float*)d_in[18];
    const float* W1      = (const float*)d_in[19];
    const float* b1      = (const float*)d_in[20];
    const float* W2      = (const float*)d_in[21];
    const float* b2      = (const float*)d_in[22];
    const float* W_cls   = (const float*)d_in[23];
    const float* b_cls   = (const float*)d_in[24];
    float* out = (float*)d_out;

    // -------- workspace layout --------
    float* ws = (float*)d_ws;
    u16*   bufWHu = (u16*)ws;                  // N x 256 bf16 (GAT phase)
    float* seqb  = ws;                         // 524544 f (transformer phase)
    u16*   Yh    = (u16*)(ws + 524544);        // 524544 u16
    u16*   QKVb  = (u16*)(ws + 1049088);       // 2112*768 u16
    u16*   Oh    = (u16*)(ws + 1860096);       // 524544 u16
    u16*   MLPHh = (u16*)(ws + 2384640);       // 2049*1024 u16
    u16*   wreg  = (u16*)(ws + 5500000);       // weights
    u16* embh  = wreg;
    u16* embl  = wreg + 2097152;
    u16* qkvh  = wreg + 4194304;
    u16* qkvl  = wreg + 5767168;
    u16* projh = wreg + 7340032;
    u16* projl = wreg + 7864320;
    u16* w1h   = wreg + 8388608;
    u16* w1l   = wreg + 10485760;
    u16* w2h   = wreg + 12582912;
    u16* w2l   = wreg + 14680064;
    u16* hH = (u16*)(ws + 16777216);           // N x 256 bf16 (GAT output)
    float* sm    = ws + 2 * 16777216;
    float* s_src = sm;
    float* s_dst = sm + 65536;
    float* emaxb = sm + 2 * 65536;
    float* denom = sm + 3 * 65536;
    float* e_buf = sm + 4 * 65536;
    float* csr_w = e_buf + 589824;
    float* Wc    = csr_w + 589824;
    float* bc    = Wc + 32768;
    int*   deg     = (int*)(bc + 256);
    int*   offs    = deg + 65536;
    int*   cur     = offs + 65536;
    int*   bsum    = cur + 65536;
    int*   csr_src = bsum + 256;
    u16*   wgTh = (u16*)(csr_src + 589824);
    u16*   wgTl = wgTh + 65536;
    u16*   wcTh = wgTh + 131072;
    u16*   wcTl = wcTh + 32768;

    // -------- GAT preprocessing --------
    gat_init<<<256, 256, 0, stream>>>(emaxb, denom, deg);
    prep_weight<<<dim3(4, 4, 1), 256, 0, stream>>>(W_gat, wgTh, wgTl, 256, 256, 0, 0, 1);
    hgemm<0,0,0,0,0,3><<<dim3(4, 2, 1), 256, 0, stream>>>(
        W_in, nullptr, wgTh, wgTl, nullptr, nullptr, Wc, nullptr, 128, 256, 256, 256);
    vecmat256<<<1, 256, 0, stream>>>(b_in, W_gat, bc);
    prep_weight<<<dim3(2, 4, 1), 256, 0, stream>>>(Wc, wcTh, wcTl, 128, 256, 0, 0, 0);
    // WH = x @ Wc + bc  (bf16 out, 1-term)
    hgemm<0,0,0,1,0,1><<<dim3(4, 1024, 1), 256, 0, stream>>>(
        x, nullptr, wcTh, nullptr, bc, nullptr, (float*)bufWHu, nullptr,
        N_NODES, 256, 128, 128);
    gat_scores<<<16384, 256, 0, stream>>>(bufWHu, a_src, a_dst, s_src, s_dst);
    edge_pass1<<<EE_EDGES / 256, 256, 0, stream>>>(ei, s_src, s_dst, e_buf, emaxb, deg);
    scan1<<<256, 256, 0, stream>>>(deg, offs, bsum);
    scan2<<<1, 256, 0, stream>>>(bsum);
    scan3<<<256, 256, 0, stream>>>(offs, bsum, cur);
    edge_pass2<<<EE_EDGES / 256, 256, 0, stream>>>(ei, e_buf, emaxb, denom, cur,
                                                   csr_src, csr_w);
    gat_aggregate<<<16384, 256, 0, stream>>>(bufWHu, csr_src, csr_w, offs, deg,
                                             denom, b_gat, hH);

    // -------- weight prep (hi only for 1-term consumers) --------
    prep_weight<<<dim3(128, 4, 1), 256, 0, stream>>>(W_emb, embh, embl, 8192, 256, 0, 0, 0);
    prep_weight<<<dim3(4, 12, 8), 256, 0, stream>>>(Wqkv, qkvh, qkvl, 256, 768,
                                                    196608, 196608, 0);
    prep_weight<<<dim3(4, 4, 8), 256, 0, stream>>>(Wproj, projh, projl, 256, 256,
                                                   65536, 65536, 0);
    prep_weight<<<dim3(4, 16, 8), 256, 0, stream>>>(W1, w1h, w1l, 256, 1024,
                                                    262144, 262144, 0);
    prep_weight<<<dim3(16, 4, 8), 256, 0, stream>>>(W2, w2h, w2l, 1024, 256,
                                                    262144, 262144, 0);

    // -------- token embedding (split-K x8, atomic, bf16 1-term) --------
    init_bias<<<2048, 256, 0, stream>>>(seqb + 256, b_emb, 2048 * 256, 255);
    hgemm<0,0,1,0,1,1><<<dim3(4, 32, 8), 256, 0, stream>>>(
        (const void*)hH, nullptr, embh, nullptr, nullptr, nullptr, seqb + 256,
        nullptr, 2048, 256, 8192, 1024);
    seed_seq<<<1, 256, 0, stream>>>(cls_tok, seqb);

    pad_zero_u32<<<95, 256, 0, stream>>>(
        (unsigned*)(QKVb + (size_t)SEQ_LEN * 768), (SEQ_PAD - SEQ_LEN) * 768 / 2);

    // -------- transformer layers (all GEMMs 1-term bf16) --------
    for (int i = 0; i < 8; ++i) {
        ln_kernel<<<SEQ_LEN, 256, 0, stream>>>(seqb, ln1_s + i * 256,
                                               ln1_b + i * 256, Yh,
                                               bproj + i * 256);
        hgemm<0,0,0,1,1,1><<<dim3(12, 33, 1), 256, 0, stream>>>(
            (const void*)Yh, nullptr, qkvh + (size_t)i * 196608, nullptr,
            bqkv + i * 768, nullptr, (float*)QKVb, nullptr, SEQ_LEN, 768, 256, 256);
        mfma_attn<<<dim3(33, NHEAD), 256, 0, stream>>>(QKVb, Oh);
        hgemm<0,0,1,0,1,1><<<dim3(4, 33, 4), 256, 0, stream>>>(
            (const void*)Oh, nullptr, projh + (size_t)i * 65536, nullptr,
            nullptr, nullptr, seqb, nullptr, SEQ_LEN, 256, 256, 64);
        ln_kernel<<<SEQ_LEN, 256, 0, stream>>>(seqb, ln2_s + i * 256,
                                               ln2_b + i * 256, Yh,
                                               b2 + i * 256);
        hgemm<1,0,0,1,1,1><<<dim3(16, 33, 1), 256, 0, stream>>>(
            (const void*)Yh, nullptr, w1h + (size_t)i * 262144, nullptr,
            b1 + i * 1024, nullptr, (float*)MLPHh, nullptr, SEQ_LEN, 1024, 256, 256);
        hgemm<0,0,1,0,1,1><<<dim3(4, 33, 4), 256, 0, stream>>>(
            (const void*)MLPHh, nullptr, w2h + (size_t)i * 262144, nullptr,
            nullptr, nullptr, seqb, nullptr, SEQ_LEN, 256, 1024, 256);
    }

    // -------- classifier head --------
    cls_head<<<1, 256, 0, stream>>>(seqb, W_cls, b_cls, out);
}

// Round 6
// 1045.028 us; speedup vs baseline: 5.4713x; 1.1625x over previous
//
#include <hip/hip_runtime.h>
#include <math.h>

#define N_NODES 65536
#define F_IN 128
#define D_MODEL 256
#define E_EDGES 524288
#define EE_EDGES 589824   /* E + N self loops */
#define SEQ_LEN 2049
#define SEQ_PAD 2112      /* 33*64 */
#define NHEAD 8
#define HDIM 32
#define NCLS 10
#define NSPLIT 4          /* attention KV splits */

typedef unsigned short u16;
typedef __attribute__((ext_vector_type(8))) short s8v;   // 8 x bf16 (4 VGPR)
typedef __attribute__((ext_vector_type(4))) float f4v;   // 4 x f32 acc

__device__ __forceinline__ u16 f2bf(float f)
{
    union { float f; unsigned u; } v; v.f = f;
    unsigned r = v.u + 0x7FFF + ((v.u >> 16) & 1);
    return (u16)(r >> 16);
}
__device__ __forceinline__ float bf2f(u16 h)
{
    union { unsigned u; float f; } v; v.u = ((unsigned)h) << 16;
    return v.f;
}

// ---------------------------------------------------------------------------
// prep: W [K,N] fp32 (row-major) -> Oh (and optionally Ol) [N,K] bf16
// ---------------------------------------------------------------------------
__global__ __launch_bounds__(256) void prep_weight(
    const float* __restrict__ W, u16* __restrict__ Oh, u16* __restrict__ Ol,
    int K, int N, long long strideW, long long strideO, int write_lo)
{
    const float* Wz = W + (size_t)blockIdx.z * strideW;
    u16* Ohz = Oh + (size_t)blockIdx.z * strideO;
    u16* Olz = Ol + (size_t)blockIdx.z * strideO;
    __shared__ u16 th[64][68];
    __shared__ u16 tl[64][68];
    int kb = blockIdx.x * 64, nb = blockIdx.y * 64;
    int t = threadIdx.x;
    int kr = t >> 4, nc = (t & 15) * 4;
#pragma unroll
    for (int i = 0; i < 4; ++i) {
        int k = kr + i * 16;
        float4 v = *(const float4*)(Wz + (size_t)(kb + k) * N + nb + nc);
        float vv[4] = {v.x, v.y, v.z, v.w};
#pragma unroll
        for (int e = 0; e < 4; ++e) {
            u16 h = f2bf(vv[e]);
            th[k][nc + e] = h;
            if (write_lo) tl[k][nc + e] = f2bf(vv[e] - bf2f(h));
        }
    }
    __syncthreads();
    int nr = t >> 4, kc = (t & 15) * 4;
#pragma unroll
    for (int i = 0; i < 4; ++i) {
        int n = nr + i * 16;
        uint2 oh;
        oh.x = (unsigned)th[kc + 0][n] | ((unsigned)th[kc + 1][n] << 16);
        oh.y = (unsigned)th[kc + 2][n] | ((unsigned)th[kc + 3][n] << 16);
        *(uint2*)(Ohz + (size_t)(nb + n) * K + kb + kc) = oh;
        if (write_lo) {
            uint2 ol;
            ol.x = (unsigned)tl[kc + 0][n] | ((unsigned)tl[kc + 1][n] << 16);
            ol.y = (unsigned)tl[kc + 2][n] | ((unsigned)tl[kc + 3][n] << 16);
            *(uint2*)(Olz + (size_t)(nb + n) * K + kb + kc) = ol;
        }
    }
}

// ---------------------------------------------------------------------------
// bf16 MFMA GEMM. TERMS=3: split hi/lo 3-term (~fp32); TERMS=1: plain bf16.
// APRE=0: A fp32 (converted in-kernel). APRE=1: A bf16 (Al2 = lo if TERMS=3).
// OB: 0 fp32 C; 1 bf16 C. ATOM=1: fp32 atomicAdd into preinited C.
// ---------------------------------------------------------------------------
template<int ACT, int RES, int ATOM, int OB, int APRE, int TERMS>
__global__ __launch_bounds__(256) void hgemm(
    const void* __restrict__ A, const u16* __restrict__ Al2,
    const u16* __restrict__ Bh, const u16* __restrict__ Bl,
    const float* __restrict__ bias, const float* __restrict__ Rsd,
    float* __restrict__ C, u16* __restrict__ C2,
    int M, int N, int K, int Kc)
{
    __shared__ __align__(16) u16 SS[(TERMS == 3 ? 4 : 2) * 2048];
    u16* const AhS = SS;
    u16* const BhS = SS + 2048;
    u16* const AlS = SS + 4096;   // TERMS==3 only
    u16* const BlS = SS + 6144;
    const int tid = threadIdx.x;
    const int bn = blockIdx.x * 64, bm = blockIdx.y * 64;
    const int kb = blockIdx.z * Kc;
    const int r = tid >> 2, cch = tid & 3;
    const int widx = r * 32 + ((cch ^ ((r >> 1) & 3)) << 3);
    const int w = tid >> 6, lane = tid & 63;
    const int wm = w >> 1, wn = w & 1;
    const int lr = lane & 15, lc = lane >> 4;
    const int ar0 = wm * 32 + lr, ar1 = ar0 + 16;
    const int nr0 = wn * 32 + lr, nr1 = nr0 + 16;
    const int ai0 = ar0 * 32 + ((lc ^ ((ar0 >> 1) & 3)) << 3);
    const int ai1 = ar1 * 32 + ((lc ^ ((ar1 >> 1) & 3)) << 3);
    const int bi0 = nr0 * 32 + ((lc ^ ((nr0 >> 1) & 3)) << 3);
    const int bi1 = nr1 * 32 + ((lc ^ ((nr1 >> 1) & 3)) << 3);

    f4v acc00 = {0.f, 0.f, 0.f, 0.f}, acc01 = acc00, acc10 = acc00, acc11 = acc00;

    const int gr = bm + r;
    const float* apf = (const float*)A + (size_t)gr * K + kb + cch * 8;
    const u16*   aph = (const u16*)A + (size_t)gr * K + kb + cch * 8;
    const u16*   apl = Al2 ? Al2 + (size_t)gr * K + kb + cch * 8 : (const u16*)0;
    const u16* bhp = Bh + (size_t)(bn + r) * K + kb + cch * 8;
    const u16* blp = (TERMS == 3) ? Bl + (size_t)(bn + r) * K + kb + cch * 8
                                  : (const u16*)0;

    for (int k0 = 0; k0 < Kc; k0 += 32) {
        s8v hv = {0, 0, 0, 0, 0, 0, 0, 0}, lv = hv;
        if (APRE) {
            if (gr < M) {
                hv = *(const s8v*)aph;
                if (TERMS == 3) lv = *(const s8v*)apl;
            }
        } else {
            float v[8] = {0.f, 0.f, 0.f, 0.f, 0.f, 0.f, 0.f, 0.f};
            if (gr < M) {
                float4 x0 = *(const float4*)apf;
                float4 x1 = *(const float4*)(apf + 4);
                v[0] = x0.x; v[1] = x0.y; v[2] = x0.z; v[3] = x0.w;
                v[4] = x1.x; v[5] = x1.y; v[6] = x1.z; v[7] = x1.w;
            }
#pragma unroll
            for (int e = 0; e < 8; ++e) {
                u16 h = f2bf(v[e]);
                hv[e] = (short)h;
                if (TERMS == 3) lv[e] = (short)f2bf(v[e] - bf2f(h));
            }
        }
        *(s8v*)&AhS[widx] = hv;
        *(s8v*)&BhS[widx] = *(const s8v*)bhp;
        if (TERMS == 3) {
            *(s8v*)&AlS[widx] = lv;
            *(s8v*)&BlS[widx] = *(const s8v*)blp;
        }
        __syncthreads();

        s8v a0h = *(s8v*)&AhS[ai0], a1h = *(s8v*)&AhS[ai1];
        s8v b0h = *(s8v*)&BhS[bi0], b1h = *(s8v*)&BhS[bi1];
        acc00 = __builtin_amdgcn_mfma_f32_16x16x32_bf16(a0h, b0h, acc00, 0, 0, 0);
        acc01 = __builtin_amdgcn_mfma_f32_16x16x32_bf16(a0h, b1h, acc01, 0, 0, 0);
        acc10 = __builtin_amdgcn_mfma_f32_16x16x32_bf16(a1h, b0h, acc10, 0, 0, 0);
        acc11 = __builtin_amdgcn_mfma_f32_16x16x32_bf16(a1h, b1h, acc11, 0, 0, 0);
        if (TERMS == 3) {
            s8v a0l = *(s8v*)&AlS[ai0], a1l = *(s8v*)&AlS[ai1];
            s8v b0l = *(s8v*)&BlS[bi0], b1l = *(s8v*)&BlS[bi1];
            acc00 = __builtin_amdgcn_mfma_f32_16x16x32_bf16(a0h, b0l, acc00, 0, 0, 0);
            acc00 = __builtin_amdgcn_mfma_f32_16x16x32_bf16(a0l, b0h, acc00, 0, 0, 0);
            acc01 = __builtin_amdgcn_mfma_f32_16x16x32_bf16(a0h, b1l, acc01, 0, 0, 0);
            acc01 = __builtin_amdgcn_mfma_f32_16x16x32_bf16(a0l, b1h, acc01, 0, 0, 0);
            acc10 = __builtin_amdgcn_mfma_f32_16x16x32_bf16(a1h, b0l, acc10, 0, 0, 0);
            acc10 = __builtin_amdgcn_mfma_f32_16x16x32_bf16(a1l, b0h, acc10, 0, 0, 0);
            acc11 = __builtin_amdgcn_mfma_f32_16x16x32_bf16(a1h, b1l, acc11, 0, 0, 0);
            acc11 = __builtin_amdgcn_mfma_f32_16x16x32_bf16(a1l, b1h, acc11, 0, 0, 0);
        }
        __syncthreads();
        apf += 32; aph += 32; if (TERMS == 3) apl += 32;
        bhp += 32; if (TERMS == 3) blp += 32;
    }

#pragma unroll
    for (int fg = 0; fg < 4; ++fg) {
        int f = fg >> 1, g = fg & 1;
        f4v a = (fg == 0) ? acc00 : (fg == 1) ? acc01 : (fg == 2) ? acc10 : acc11;
        int col = bn + wn * 32 + g * 16 + lr;
        int row0 = bm + wm * 32 + f * 16 + lc * 4;
#pragma unroll
        for (int j = 0; j < 4; ++j) {
            int rr = row0 + j;
            if (rr < M) {
                float vv = a[j];
                if (ATOM) {
                    atomicAdd(&C[(size_t)rr * N + col], vv);
                } else {
                    if (bias) vv += bias[col];
                    if (ACT == 1) vv = 0.5f * vv * (1.0f + erff(vv * 0.70710678118654752f));
                    if (RES) vv += Rsd[(size_t)rr * N + col];
                    if (OB == 1) ((u16*)C)[(size_t)rr * N + col] = f2bf(vv);
                    else         C[(size_t)rr * N + col] = vv;
                }
            }
        }
    }
    (void)C2;
}

__global__ void init_bias(float* __restrict__ C, const float* __restrict__ bias,
                          int total, int nmask)
{
    int i = blockIdx.x * 256 + threadIdx.x;
    if (i < total) C[i] = bias[i & nmask];
}

__global__ void pad_zero_u32(unsigned* __restrict__ p, int n)
{
    int i = blockIdx.x * 256 + threadIdx.x;
    if (i < n) p[i] = 0u;
}

__global__ void vecmat256(const float* __restrict__ v, const float* __restrict__ W,
                          float* __restrict__ out)
{
    int n = threadIdx.x;
    float acc = 0.f;
    for (int k = 0; k < 256; ++k) acc += v[k] * W[k * 256 + n];
    out[n] = acc;
}

// ---------------------------------------------------------------------------
// GAT pieces
// ---------------------------------------------------------------------------
__global__ void gat_init(float* __restrict__ emax, float* __restrict__ denom,
                         int* __restrict__ deg)
{
    int i = blockIdx.x * 256 + threadIdx.x;
    emax[i] = -1e30f;
    denom[i] = 0.f;
    deg[i] = 0;
}

__global__ __launch_bounds__(256) void gat_scores(
    const u16* __restrict__ WH, const float* __restrict__ a_src,
    const float* __restrict__ a_dst, float* __restrict__ s_src,
    float* __restrict__ s_dst)
{
    int gid = blockIdx.x * 256 + threadIdx.x;
    int node = gid >> 6;
    int lane = gid & 63;
    uint2 rv = *(const uint2*)(WH + (size_t)node * D_MODEL + (lane << 2));
    float d0 = __uint_as_float(rv.x << 16);
    float d1 = __uint_as_float(rv.x & 0xffff0000u);
    float d2 = __uint_as_float(rv.y << 16);
    float d3 = __uint_as_float(rv.y & 0xffff0000u);
    float4 asv = *(const float4*)(a_src + (lane << 2));
    float4 adv = *(const float4*)(a_dst + (lane << 2));
    float as = d0 * asv.x + d1 * asv.y + d2 * asv.z + d3 * asv.w;
    float ad = d0 * adv.x + d1 * adv.y + d2 * adv.z + d3 * adv.w;
#pragma unroll
    for (int off = 32; off; off >>= 1) {
        as += __shfl_down(as, off);
        ad += __shfl_down(ad, off);
    }
    if (lane == 0) { s_src[node] = as; s_dst[node] = ad; }
}

__device__ __forceinline__ void atomicMaxFloat(float* addr, float val)
{
    int* ai = (int*)addr;
    int old = __float_as_int(*addr);
    while (__int_as_float(old) < val) {
        int prev = atomicCAS(ai, old, __float_as_int(val));
        if (prev == old) break;
        old = prev;
    }
}

__global__ void edge_pass1(const int* __restrict__ ei, const float* __restrict__ s_src,
                           const float* __restrict__ s_dst, float* __restrict__ e_buf,
                           float* __restrict__ emax, int* __restrict__ deg)
{
    int j = blockIdx.x * 256 + threadIdx.x;
    if (j >= EE_EDGES) return;
    int s, d;
    if (j < E_EDGES) { s = ei[j]; d = ei[E_EDGES + j]; }
    else { s = d = j - E_EDGES; }
    float e = s_src[s] + s_dst[d];
    e = (e > 0.f) ? e : 0.2f * e;
    e_buf[j] = e;
    atomicMaxFloat(&emax[d], e);
    atomicAdd(&deg[d], 1);
}

__global__ void scan1(const int* __restrict__ in, int* __restrict__ out_excl,
                      int* __restrict__ bsum)
{
    __shared__ int s[256];
    int t = threadIdx.x;
    int i = blockIdx.x * 256 + t;
    int v = in[i];
    s[t] = v;
    __syncthreads();
    for (int off = 1; off < 256; off <<= 1) {
        int u = (t >= off) ? s[t - off] : 0;
        __syncthreads();
        s[t] += u;
        __syncthreads();
    }
    out_excl[i] = s[t] - v;
    if (t == 255) bsum[blockIdx.x] = s[255];
}

__global__ void scan2(int* __restrict__ bsum)
{
    __shared__ int s[256];
    int t = threadIdx.x;
    int v = bsum[t];
    s[t] = v;
    __syncthreads();
    for (int off = 1; off < 256; off <<= 1) {
        int u = (t >= off) ? s[t - off] : 0;
        __syncthreads();
        s[t] += u;
        __syncthreads();
    }
    bsum[t] = s[t] - v;
}

__global__ void scan3(int* __restrict__ offs, const int* __restrict__ bsum,
                      int* __restrict__ cur)
{
    int i = blockIdx.x * 256 + threadIdx.x;
    int v = offs[i] + bsum[blockIdx.x];
    offs[i] = v;
    cur[i] = v;
}

__global__ void edge_pass2(const int* __restrict__ ei, const float* __restrict__ e_buf,
                           const float* __restrict__ emax, float* __restrict__ denom,
                           int* __restrict__ cur, int* __restrict__ csr_src,
                           float* __restrict__ csr_w)
{
    int j = blockIdx.x * 256 + threadIdx.x;
    if (j >= EE_EDGES) return;
    int s, d;
    if (j < E_EDGES) { s = ei[j]; d = ei[E_EDGES + j]; }
    else { s = d = j - E_EDGES; }
    float ee = __expf(e_buf[j] - emax[d]);
    atomicAdd(&denom[d], ee);
    int pos = atomicAdd(&cur[d], 1);
    csr_src[pos] = s;
    csr_w[pos] = ee;
}

// bf16 WH gather -> h bf16 (single)
__global__ __launch_bounds__(256) void gat_aggregate(
    const u16* __restrict__ WH, const int* __restrict__ csr_src,
    const float* __restrict__ csr_w, const int* __restrict__ offs,
    const int* __restrict__ deg, const float* __restrict__ denom,
    const float* __restrict__ b_gat, u16* __restrict__ hH)
{
    int gid = blockIdx.x * 256 + threadIdx.x;
    int node = gid >> 6;
    int lane = gid & 63;
    float inv = 1.0f / denom[node];
    float a0 = 0.f, a1 = 0.f, a2 = 0.f, a3 = 0.f;
    int s0 = offs[node], e0 = s0 + deg[node];
    for (int k = s0; k < e0; ++k) {
        int src = csr_src[k];
        float alpha = csr_w[k] * inv;
        uint2 rv = *(const uint2*)(WH + (size_t)src * D_MODEL + (lane << 2));
        a0 += alpha * __uint_as_float(rv.x << 16);
        a1 += alpha * __uint_as_float(rv.x & 0xffff0000u);
        a2 += alpha * __uint_as_float(rv.y << 16);
        a3 += alpha * __uint_as_float(rv.y & 0xffff0000u);
    }
    float4 bg = *(const float4*)(b_gat + (lane << 2));
    float v0 = a0 + bg.x, v1 = a1 + bg.y, v2 = a2 + bg.z, v3 = a3 + bg.w;
    uint2 ho;
    ho.x = (unsigned)f2bf(v0) | ((unsigned)f2bf(v1) << 16);
    ho.y = (unsigned)f2bf(v2) | ((unsigned)f2bf(v3) << 16);
    *(uint2*)(hH + (size_t)node * D_MODEL + (lane << 2)) = ho;
}

// ---------------------------------------------------------------------------
// LayerNorm: writes Yh (bf16) and folds next GEMM's bias into seqio in place.
// ---------------------------------------------------------------------------
__global__ __launch_bounds__(256) void ln_kernel(
    float* __restrict__ seqio, const float* __restrict__ sc,
    const float* __restrict__ bi, u16* __restrict__ Yh,
    const float* __restrict__ badd)
{
    int row = blockIdx.x;
    int t = threadIdx.x;
    float x = seqio[(size_t)row * 256 + t];
    float sum = x, sq = x * x;
#pragma unroll
    for (int off = 32; off; off >>= 1) {
        sum += __shfl_down(sum, off);
        sq  += __shfl_down(sq, off);
    }
    __shared__ float rs[4], rq[4];
    if ((t & 63) == 0) { rs[t >> 6] = sum; rq[t >> 6] = sq; }
    __syncthreads();
    sum = rs[0] + rs[1] + rs[2] + rs[3];
    sq  = rq[0] + rq[1] + rq[2] + rq[3];
    float mean = sum * (1.f / 256.f);
    float var  = sq * (1.f / 256.f) - mean * mean;
    float r = rsqrtf(var + 1e-5f);
    float y = (x - mean) * r * sc[t] + bi[t];
    Yh[(size_t)row * 256 + t] = f2bf(y);
    seqio[(size_t)row * 256 + t] = x + badd[t];
}

// ---------------------------------------------------------------------------
// Split-KV MFMA flash attention. Grid (33, 8, NSPLIT).
// Block (qb,h,s): q rows qb*64..+63, kv tiles [33*s/4, 33*(s+1)/4).
// Writes UNNORMALIZED partial O (fp32) + per-(q,h) m,l to workspace.
// ---------------------------------------------------------------------------
__global__ __launch_bounds__(256) void mfma_attn_split(
    const u16* __restrict__ QKV, float* __restrict__ Opart,
    float* __restrict__ Mpart, float* __restrict__ Lpart)
{
    __shared__ __align__(16) u16 Ks[64 * 32];
    __shared__ __align__(16) u16 Vt[32 * 72];
    __shared__ __align__(16) u16 Ps[4 * 16 * 72];
    const int tid = threadIdx.x;
    const int w = tid >> 6, lane = tid & 63;
    const int g = lane >> 4, ql = lane & 15;
    const int h = blockIdx.y;
    const int sp = blockIdx.z;
    const int t0 = (33 * sp) / NSPLIT, t1 = (33 * (sp + 1)) / NSPLIT;
    const int qbase = blockIdx.x * 64 + w * 16;
    const float scale = 0.17677669529663687f;

    int qrow = qbase + ql; if (qrow > SEQ_LEN - 1) qrow = SEQ_LEN - 1;
    const s8v qfrag = *(const s8v*)(QKV + (size_t)qrow * 768 + h * 32 + g * 8);

    f4v o0 = {0.f, 0.f, 0.f, 0.f}, o1 = o0;
    float m[4], l[4];
#pragma unroll
    for (int r = 0; r < 4; ++r) { m[r] = -1e30f; l[r] = 0.f; }

    const int sr = tid >> 2, sc_ = tid & 3;
    const int kslot = sc_ ^ ((sr >> 1) & 3);
    u16* const psw = &Ps[w * 1152];

    for (int t = t0; t < t1; ++t) {
        __syncthreads();
        {
            int grow = t * 64 + sr;
            const u16* kp = QKV + (size_t)grow * 768 + 256 + h * 32 + sc_ * 8;
            s8v kvv = *(const s8v*)kp;
            s8v vvv = *(const s8v*)(kp + 256);
            *(s8v*)&Ks[sr * 32 + kslot * 8] = kvv;
#pragma unroll
            for (int e = 0; e < 8; ++e) Vt[(sc_ * 8 + e) * 72 + sr] = (u16)vvv[e];
        }
        __syncthreads();

        f4v s[4];
        const f4v zz = {0.f, 0.f, 0.f, 0.f};
#pragma unroll
        for (int c = 0; c < 4; ++c) {
            int kvloc = c * 16 + ql;
            s8v kf = *(s8v*)&Ks[kvloc * 32 + ((g ^ ((kvloc >> 1) & 3)) << 3)];
            s[c] = __builtin_amdgcn_mfma_f32_16x16x32_bf16(qfrag, kf, zz, 0, 0, 0);
            int kvg = t * 64 + kvloc;
            bool valid = (kvg < SEQ_LEN);
#pragma unroll
            for (int r = 0; r < 4; ++r)
                s[c][r] = valid ? s[c][r] * scale : -1e30f;
        }

        float mloc[4];
#pragma unroll
        for (int r = 0; r < 4; ++r) {
            float v = fmaxf(fmaxf(s[0][r], s[1][r]), fmaxf(s[2][r], s[3][r]));
            v = fmaxf(v, __shfl_xor(v, 1));
            v = fmaxf(v, __shfl_xor(v, 2));
            v = fmaxf(v, __shfl_xor(v, 4));
            v = fmaxf(v, __shfl_xor(v, 8));
            mloc[r] = v;
        }
        float fac[4];
#pragma unroll
        for (int r = 0; r < 4; ++r) {
            float mn = fmaxf(m[r], mloc[r]);
            fac[r] = __expf(m[r] - mn);
            m[r] = mn;
        }
#pragma unroll
        for (int c = 0; c < 4; ++c)
#pragma unroll
            for (int r = 0; r < 4; ++r)
                s[c][r] = __expf(s[c][r] - m[r]);
#pragma unroll
        for (int r = 0; r < 4; ++r) {
            float ls = s[0][r] + s[1][r] + s[2][r] + s[3][r];
            ls += __shfl_xor(ls, 1);
            ls += __shfl_xor(ls, 2);
            ls += __shfl_xor(ls, 4);
            ls += __shfl_xor(ls, 8);
            l[r] = l[r] * fac[r] + ls;
            o0[r] *= fac[r];
            o1[r] *= fac[r];
        }

#pragma unroll
        for (int c = 0; c < 4; ++c)
#pragma unroll
            for (int r = 0; r < 4; ++r)
                psw[(g * 4 + r) * 72 + c * 16 + ql] = f2bf(s[c][r]);

#pragma unroll
        for (int kch = 0; kch < 2; ++kch) {
            s8v pf = *(s8v*)&psw[ql * 72 + kch * 32 + g * 8];
            s8v v0 = *(s8v*)&Vt[ql * 72 + kch * 32 + g * 8];
            s8v v1 = *(s8v*)&Vt[(16 + ql) * 72 + kch * 32 + g * 8];
            o0 = __builtin_amdgcn_mfma_f32_16x16x32_bf16(pf, v0, o0, 0, 0, 0);
            o1 = __builtin_amdgcn_mfma_f32_16x16x32_bf16(pf, v1, o1, 0, 0, 0);
        }
    }

#pragma unroll
    for (int r = 0; r < 4; ++r) {
        int q = qbase + g * 4 + r;
        if (q < SEQ_LEN) {
            size_t base = ((size_t)sp * SEQ_PAD + q) * 256 + h * 32;
            Opart[base + ql] = o0[r];
            Opart[base + 16 + ql] = o1[r];
            if (ql == 0) {
                Mpart[((size_t)sp * SEQ_PAD + q) * NHEAD + h] = m[r];
                Lpart[((size_t)sp * SEQ_PAD + q) * NHEAD + h] = l[r];
            }
        }
    }
}

// Combine NSPLIT partials -> bf16 O. Grid (SEQ_LEN), 256 thr (h = t>>5).
__global__ __launch_bounds__(256) void attn_combine(
    const float* __restrict__ Opart, const float* __restrict__ Mpart,
    const float* __restrict__ Lpart, u16* __restrict__ Oh)
{
    int q = blockIdx.x;
    int t = threadIdx.x;
    int h = t >> 5, d = t & 31;
    float ms[NSPLIT], ls[NSPLIT];
    float M = -1e30f;
#pragma unroll
    for (int s = 0; s < NSPLIT; ++s) {
        ms[s] = Mpart[((size_t)s * SEQ_PAD + q) * NHEAD + h];
        ls[s] = Lpart[((size_t)s * SEQ_PAD + q) * NHEAD + h];
        M = fmaxf(M, ms[s]);
    }
    float L = 0.f, O = 0.f;
#pragma unroll
    for (int s = 0; s < NSPLIT; ++s) {
        float f = __expf(ms[s] - M);
        L += ls[s] * f;
        O += Opart[((size_t)s * SEQ_PAD + q) * 256 + h * 32 + d] * f;
    }
    Oh[(size_t)q * 256 + h * 32 + d] = f2bf(O / L);
}

__global__ void seed_seq(const float* __restrict__ cls, float* __restrict__ seq)
{
    seq[threadIdx.x] = cls[threadIdx.x];
}

__global__ void cls_head(const float* __restrict__ seq, const float* __restrict__ W,
                         const float* __restrict__ b, float* __restrict__ out)
{
    __shared__ float s[256];
    int t = threadIdx.x;
    s[t] = seq[t];
    __syncthreads();
    if (t < NCLS) {
        float acc = b[t];
        for (int k = 0; k < 256; ++k) acc += s[k] * W[k * NCLS + t];
        out[t] = acc;
    }
}

// ---------------------------------------------------------------------------
extern "C" void kernel_launch(void* const* d_in, const int* in_sizes, int n_in,
                              void* d_out, int out_size, void* d_ws, size_t ws_size,
                              hipStream_t stream)
{
    (void)in_sizes; (void)n_in; (void)out_size; (void)ws_size;
    const float* x       = (const float*)d_in[0];
    const int*   ei      = (const int*)d_in[1];
    const float* W_in    = (const float*)d_in[2];
    const float* b_in    = (const float*)d_in[3];
    const float* W_gat   = (const float*)d_in[4];
    const float* a_src   = (const float*)d_in[5];
    const float* a_dst   = (const float*)d_in[6];
    const float* b_gat   = (const float*)d_in[7];
    const float* W_emb   = (const float*)d_in[8];
    const float* b_emb   = (const float*)d_in[9];
    const float* cls_tok = (const float*)d_in[10];
    const float* ln1_s   = (const float*)d_in[11];
    const float* ln1_b   = (const float*)d_in[12];
    const float* Wqkv    = (const float*)d_in[13];
    const float* bqkv    = (const float*)d_in[14];
    const float* Wproj   = (const float*)d_in[15];
    const float* bproj   = (const float*)d_in[16];
    const float* ln2_s   = (const float*)d_in[17];
    const float* ln2_b   = (const float*)d_in[18];
    const float* W1      = (const float*)d_in[19];
    const float* b1      = (const float*)d_in[20];
    const float* W2      = (const float*)d_in[21];
    const float* b2      = (const float*)d_in[22];
    const float* W_cls   = (const float*)d_in[23];
    const float* b_cls   = (const float*)d_in[24];
    float* out = (float*)d_out;

    // -------- workspace layout --------
    float* ws = (float*)d_ws;
    u16*   bufWHu = (u16*)ws;                  // N x 256 bf16 (GAT phase)
    float* seqb  = ws;                         // 524544 f (transformer phase)
    u16*   Yh    = (u16*)(ws + 524544);        // 524544 u16
    u16*   QKVb  = (u16*)(ws + 1049088);       // 2112*768 u16
    u16*   Oh    = (u16*)(ws + 1860096);       // 524544 u16
    u16*   MLPHh = (u16*)(ws + 2384640);       // 2049*1024 u16
    u16*   wreg  = (u16*)(ws + 5500000);       // weights
    u16* embh  = wreg;
    u16* embl  = wreg + 2097152;
    u16* qkvh  = wreg + 4194304;
    u16* qkvl  = wreg + 5767168;
    u16* projh = wreg + 7340032;
    u16* projl = wreg + 7864320;
    u16* w1h   = wreg + 8388608;
    u16* w1l   = wreg + 10485760;
    u16* w2h   = wreg + 12582912;
    u16* w2l   = wreg + 14680064;
    // region B: hH (GAT output, bf16) — dead after embedding GEMM;
    // attention partials alias the same region (attn runs strictly later).
    u16*   hH    = (u16*)(ws + 16777216);      // N x 256 bf16
    float* Opart = ws + 16777216;              // NSPLIT*2112*256 = 2162688 f
    float* Mpart = Opart + (size_t)NSPLIT * SEQ_PAD * 256;   // NSPLIT*2112*8
    float* Lpart = Mpart + (size_t)NSPLIT * SEQ_PAD * NHEAD;
    float* sm    = ws + 2 * 16777216;
    float* s_src = sm;
    float* s_dst = sm + 65536;
    float* emaxb = sm + 2 * 65536;
    float* denom = sm + 3 * 65536;
    float* e_buf = sm + 4 * 65536;
    float* csr_w = e_buf + 589824;
    float* Wc    = csr_w + 589824;
    float* bc    = Wc + 32768;
    int*   deg     = (int*)(bc + 256);
    int*   offs    = deg + 65536;
    int*   cur     = offs + 65536;
    int*   bsum    = cur + 65536;
    int*   csr_src = bsum + 256;
    u16*   wgTh = (u16*)(csr_src + 589824);
    u16*   wgTl = wgTh + 65536;
    u16*   wcTh = wgTh + 131072;
    u16*   wcTl = wcTh + 32768;

    // -------- GAT preprocessing --------
    gat_init<<<256, 256, 0, stream>>>(emaxb, denom, deg);
    prep_weight<<<dim3(4, 4, 1), 256, 0, stream>>>(W_gat, wgTh, wgTl, 256, 256, 0, 0, 1);
    hgemm<0,0,0,0,0,3><<<dim3(4, 2, 1), 256, 0, stream>>>(
        W_in, nullptr, wgTh, wgTl, nullptr, nullptr, Wc, nullptr, 128, 256, 256, 256);
    vecmat256<<<1, 256, 0, stream>>>(b_in, W_gat, bc);
    prep_weight<<<dim3(2, 4, 1), 256, 0, stream>>>(Wc, wcTh, wcTl, 128, 256, 0, 0, 0);
    // WH = x @ Wc + bc  (bf16 out, 1-term)
    hgemm<0,0,0,1,0,1><<<dim3(4, 1024, 1), 256, 0, stream>>>(
        x, nullptr, wcTh, nullptr, bc, nullptr, (float*)bufWHu, nullptr,
        N_NODES, 256, 128, 128);
    gat_scores<<<16384, 256, 0, stream>>>(bufWHu, a_src, a_dst, s_src, s_dst);
    edge_pass1<<<EE_EDGES / 256, 256, 0, stream>>>(ei, s_src, s_dst, e_buf, emaxb, deg);
    scan1<<<256, 256, 0, stream>>>(deg, offs, bsum);
    scan2<<<1, 256, 0, stream>>>(bsum);
    scan3<<<256, 256, 0, stream>>>(offs, bsum, cur);
    edge_pass2<<<EE_EDGES / 256, 256, 0, stream>>>(ei, e_buf, emaxb, denom, cur,
                                                   csr_src, csr_w);
    gat_aggregate<<<16384, 256, 0, stream>>>(bufWHu, csr_src, csr_w, offs, deg,
                                             denom, b_gat, hH);

    // -------- weight prep (hi only for 1-term consumers) --------
    prep_weight<<<dim3(128, 4, 1), 256, 0, stream>>>(W_emb, embh, embl, 8192, 256, 0, 0, 0);
    prep_weight<<<dim3(4, 12, 8), 256, 0, stream>>>(Wqkv, qkvh, qkvl, 256, 768,
                                                    196608, 196608, 0);
    prep_weight<<<dim3(4, 4, 8), 256, 0, stream>>>(Wproj, projh, projl, 256, 256,
                                                   65536, 65536, 0);
    prep_weight<<<dim3(4, 16, 8), 256, 0, stream>>>(W1, w1h, w1l, 256, 1024,
                                                    262144, 262144, 0);
    prep_weight<<<dim3(16, 4, 8), 256, 0, stream>>>(W2, w2h, w2l, 1024, 256,
                                                    262144, 262144, 0);

    // -------- token embedding (split-K x8, atomic, bf16 1-term) --------
    init_bias<<<2048, 256, 0, stream>>>(seqb + 256, b_emb, 2048 * 256, 255);
    hgemm<0,0,1,0,1,1><<<dim3(4, 32, 8), 256, 0, stream>>>(
        (const void*)hH, nullptr, embh, nullptr, nullptr, nullptr, seqb + 256,
        nullptr, 2048, 256, 8192, 1024);
    seed_seq<<<1, 256, 0, stream>>>(cls_tok, seqb);

    pad_zero_u32<<<95, 256, 0, stream>>>(
        (unsigned*)(QKVb + (size_t)SEQ_LEN * 768), (SEQ_PAD - SEQ_LEN) * 768 / 2);

    // -------- transformer layers (all GEMMs 1-term bf16) --------
    for (int i = 0; i < 8; ++i) {
        ln_kernel<<<SEQ_LEN, 256, 0, stream>>>(seqb, ln1_s + i * 256,
                                               ln1_b + i * 256, Yh,
                                               bproj + i * 256);
        hgemm<0,0,0,1,1,1><<<dim3(12, 33, 1), 256, 0, stream>>>(
            (const void*)Yh, nullptr, qkvh + (size_t)i * 196608, nullptr,
            bqkv + i * 768, nullptr, (float*)QKVb, nullptr, SEQ_LEN, 768, 256, 256);
        mfma_attn_split<<<dim3(33, NHEAD, NSPLIT), 256, 0, stream>>>(
            QKVb, Opart, Mpart, Lpart);
        attn_combine<<<SEQ_LEN, 256, 0, stream>>>(Opart, Mpart, Lpart, Oh);
        hgemm<0,0,1,0,1,1><<<dim3(4, 33, 4), 256, 0, stream>>>(
            (const void*)Oh, nullptr, projh + (size_t)i * 65536, nullptr,
            nullptr, nullptr, seqb, nullptr, SEQ_LEN, 256, 256, 64);
        ln_kernel<<<SEQ_LEN, 256, 0, stream>>>(seqb, ln2_s + i * 256,
                                               ln2_b + i * 256, Yh,
                                               b2 + i * 256);
        hgemm<1,0,0,1,1,1><<<dim3(16, 33, 1), 256, 0, stream>>>(
            (const void*)Yh, nullptr, w1h + (size_t)i * 262144, nullptr,
            b1 + i * 1024, nullptr, (float*)MLPHh, nullptr, SEQ_LEN, 1024, 256, 256);
        hgemm<0,0,1,0,1,1><<<dim3(4, 33, 4), 256, 0, stream>>>(
            (const void*)MLPHh, nullptr, w2h + (size_t)i * 262144, nullptr,
            nullptr, nullptr, seqb, nullptr, SEQ_LEN, 256, 1024, 256);
    }

    // -------- classifier head --------
    cls_head<<<1, 256, 0, stream>>>(seqb, W_cls, b_cls, out);
}